// Round 6
// baseline (483.480 us; speedup 1.0000x reference)
//
#include <hip/hip_runtime.h>
#include <math.h>

#define NN 65536      // nodes
#define NE 524288     // edges
#define NG 256        // graphs (256 contiguous nodes each)
#define SLOPE 0.01f

__device__ __forceinline__ float lrelu(float v){ return v > 0.f ? v : SLOPE*v; }

// ---------- block reductions (256-thread blocks = 4 waves) ----------
__device__ __forceinline__ float blockMax4(float v, float* s4){
  #pragma unroll
  for(int o=32;o>0;o>>=1) v = fmaxf(v, __shfl_down(v, o, 64));
  int t = threadIdx.x;
  __syncthreads();
  if((t&63)==0) s4[t>>6] = v;
  __syncthreads();
  return fmaxf(fmaxf(s4[0], s4[1]), fmaxf(s4[2], s4[3]));
}
__device__ __forceinline__ float blockSum4(float v, float* s4){
  #pragma unroll
  for(int o=32;o>0;o>>=1) v += __shfl_down(v, o, 64);
  int t = threadIdx.x;
  __syncthreads();
  if((t&63)==0) s4[t>>6] = v;
  __syncthreads();
  return (s4[0]+s4[1])+(s4[2]+s4[3]);
}

// ---------- CSR build (by dst) ----------
__global__ __launch_bounds__(256) void k_count(const int* __restrict__ ei, int* __restrict__ deg){
  int e = blockIdx.x*256 + threadIdx.x;
  if(e < NE) atomicAdd(&deg[ei[NE + e]], 1);
}

__global__ __launch_bounds__(1024) void k_scan(const int* __restrict__ deg,
      int* __restrict__ offs, int* __restrict__ cursor){
  __shared__ int part[1024];
  int t = threadIdx.x;
  const int4* d4 = (const int4*)(deg + t*64);
  int4 buf[16];
  int s=0;
  #pragma unroll
  for(int i=0;i<16;i++){ buf[i]=d4[i]; s += buf[i].x+buf[i].y+buf[i].z+buf[i].w; }
  part[t]=s;
  __syncthreads();
  for(int off=1; off<1024; off<<=1){
    int v = (t>=off)? part[t-off] : 0;
    __syncthreads();
    part[t] += v;
    __syncthreads();
  }
  int run = (t==0)? 0 : part[t-1];
  #pragma unroll
  for(int i=0;i<16;i++){
    int4 d = buf[i];
    int4 o;
    o.x = run; run += d.x;
    o.y = run; run += d.y;
    o.z = run; run += d.z;
    o.w = run; run += d.w;
    ((int4*)(offs + t*64))[i] = o;
    ((int4*)(cursor + t*64))[i] = o;
  }
  if(t==1023) offs[NN] = run;
}

__global__ __launch_bounds__(256) void k_scatter(const int* __restrict__ ei,
      int* __restrict__ cursor, int* __restrict__ csr){
  int e = blockIdx.x*256 + threadIdx.x;
  if(e < NE){
    int d = ei[NE + e];
    int p = atomicAdd(&cursor[d], 1);
    csr[p] = ei[e];
  }
}

// ---------- conv0: agg[i] = max over in-edges of x[src], else 0 ----------
__global__ __launch_bounds__(256) void k_agg0(const float* __restrict__ x,
    const int* __restrict__ offs, const int* __restrict__ csr, float* __restrict__ agg0){
  int tid = blockIdx.x*256 + threadIdx.x;
  int node = tid>>4, q = tid&15;        // 16 threads (float4 lanes) per node
  int e0 = offs[node], e1 = offs[node+1];
  float4 acc = make_float4(0.f,0.f,0.f,0.f);
  if(e0 < e1){
    acc = make_float4(-INFINITY,-INFINITY,-INFINITY,-INFINITY);
    int e = e0;
    for(; e+7 < e1; e += 8){            // 8 independent gathers in flight
      int si[8];
      #pragma unroll
      for(int u=0;u<8;u++) si[u] = csr[e+u];
      float4 v[8];
      #pragma unroll
      for(int u=0;u<8;u++) v[u] = ((const float4*)x)[si[u]*16 + q];
      #pragma unroll
      for(int u=0;u<8;u++){
        acc.x=fmaxf(acc.x,v[u].x); acc.y=fmaxf(acc.y,v[u].y);
        acc.z=fmaxf(acc.z,v[u].z); acc.w=fmaxf(acc.w,v[u].w);
      }
    }
    for(; e < e1; e++){
      int s0 = csr[e];
      float4 v0 = ((const float4*)x)[s0*16 + q];
      acc.x=fmaxf(acc.x,v0.x); acc.y=fmaxf(acc.y,v0.y);
      acc.z=fmaxf(acc.z,v0.z); acc.w=fmaxf(acc.w,v0.w);
    }
  }
  ((float4*)agg0)[node*16 + q] = acc;
}

// ---------- conv0 matmul: cur = lrelu(agg0@Wrel^T + x@Wroot^T + b0) ----------
// Scalar-operand GEMM: thread = output column j (W row in 128 VGPRs); node is
// wave-uniform -> A-row loads take the SMEM/broadcast path (separate pipe from
// VALU, no LDS). 4 accumulators break the 4-cyc FMA dep chain. NO launch_bounds
// occupancy cap (round-2/5 lesson: a cap here spills W/acc to scratch).
__global__ __launch_bounds__(256) void k_conv0mm(
    const float* __restrict__ agg0, const float* __restrict__ x,
    const float* __restrict__ Wrel, const float* __restrict__ Wroot,
    const float* __restrict__ b0, float* __restrict__ cur,
    float* __restrict__ bnsum, float* __restrict__ bnsq){
  const int t = threadIdx.x;
  const int j = t & 127;                                   // output column
  const int s = __builtin_amdgcn_readfirstlane(t >> 7);    // node-stream (uniform/wave)
  float wreg[128];
  {
    const float4* wr4 = (const float4*)(Wrel + (size_t)j*64);
    const float4* wo4 = (const float4*)(Wroot + (size_t)j*64);
    #pragma unroll
    for(int i=0;i<16;i++){
      *(float4*)&wreg[i*4]    = wr4[i];
      *(float4*)&wreg[64+i*4] = wo4[i];
    }
  }
  const float bj = b0[j];
  float cs = 0.f, cq = 0.f;
  const int nbase = blockIdx.x*64 + s*32;                  // 1024 blocks x 64 nodes
  #pragma unroll 1
  for(int it=0; it<32; it++){
    const int node = nbase + it;                           // uniform per wave
    const float* __restrict__ ra = agg0 + (size_t)node*64;
    const float* __restrict__ rx = x    + (size_t)node*64;
    float a0=0.f, a1=0.f, a2=0.f, a3=0.f;
    #pragma unroll
    for(int k=0;k<64;k+=4){
      a0 = fmaf(ra[k+0], wreg[k+0], a0);
      a1 = fmaf(ra[k+1], wreg[k+1], a1);
      a2 = fmaf(ra[k+2], wreg[k+2], a2);
      a3 = fmaf(ra[k+3], wreg[k+3], a3);
    }
    #pragma unroll
    for(int k=0;k<64;k+=4){
      a0 = fmaf(rx[k+0], wreg[64+k+0], a0);
      a1 = fmaf(rx[k+1], wreg[64+k+1], a1);
      a2 = fmaf(rx[k+2], wreg[64+k+2], a2);
      a3 = fmaf(rx[k+3], wreg[64+k+3], a3);
    }
    float o = lrelu((a0+a1)+(a2+a3) + bj);
    cur[(size_t)node*128 + j] = o;
    cs += o; cq += o*o;
  }
  atomicAdd(&bnsum[j], cs);
  atomicAdd(&bnsq[j], cq);
}

// ---------- streaming update + per-node pool scores ----------
template<int MODE>
__global__ __launch_bounds__(256) void k_stream(
    float* __restrict__ cur, const float* __restrict__ onew,
    const unsigned char* __restrict__ keepin,
    const float* __restrict__ bnsA, const float* __restrict__ bnqA,
    const float* __restrict__ g1, const float* __restrict__ b1,
    const float* __restrict__ bns0, const float* __restrict__ bnq0,
    const float* __restrict__ g0, const float* __restrict__ b0bn,
    const float* __restrict__ pw, float* __restrict__ scores){
  __shared__ __align__(16) float w[4][128];
  __shared__ __align__(16) float sc1[128], of1[128], sc0[128], of0[128];
  const int t = threadIdx.x;
  if(t<128){
    if(MODE>=1){
      float mu = bnsA[t]*(1.0f/NN);
      float var = bnqA[t]*(1.0f/NN) - mu*mu;
      float s = g1[t]*rsqrtf(var+1e-5f);
      sc1[t]=s; of1[t]=b1[t]-mu*s;
    }
    if(MODE<=1){
      float mu0 = bns0[t]*(1.0f/NN);
      float var0 = bnq0[t]*(1.0f/NN) - mu0*mu0;
      float s0 = g0[t]*rsqrtf(var0+1e-5f);
      sc0[t]=s0; of0[t]=b0bn[t]-mu0*s0;
    }
  }
  __syncthreads();
  for(int i=t;i<512;i+=256){
    float wv = pw[i];
    if(MODE==0) wv *= sc0[i&127];
    w[i>>7][i&127]=wv;
  }
  __syncthreads();
  const int tid = blockIdx.x*256 + t;
  const int n = tid>>5, k = tid&31;
  float4 v = ((const float4*)cur)[tid];
  if(MODE>=1){
    const int h = k>>3;
    float4 nv = make_float4(0.f,0.f,0.f,0.f);
    if((keepin[n]>>h)&1) nv = ((const float4*)onew)[tid];
    float4 s1 = *(const float4*)&sc1[k*4];
    float4 o1 = *(const float4*)&of1[k*4];
    if(MODE==1){
      float4 s0 = *(const float4*)&sc0[k*4];
      float4 o0 = *(const float4*)&of0[k*4];
      v.x = 0.5f*(s0.x*v.x+o0.x) + 0.25f*(s1.x*nv.x+o1.x);
      v.y = 0.5f*(s0.y*v.y+o0.y) + 0.25f*(s1.y*nv.y+o1.y);
      v.z = 0.5f*(s0.z*v.z+o0.z) + 0.25f*(s1.z*nv.z+o1.z);
      v.w = 0.5f*(s0.w*v.w+o0.w) + 0.25f*(s1.w*nv.w+o1.w);
    } else {
      v.x = 0.5f*v.x + 0.25f*(s1.x*nv.x+o1.x);
      v.y = 0.5f*v.y + 0.25f*(s1.y*nv.y+o1.y);
      v.z = 0.5f*v.z + 0.25f*(s1.z*nv.z+o1.z);
      v.w = 0.5f*v.w + 0.25f*(s1.w*nv.w+o1.w);
    }
    ((float4*)cur)[tid] = v;
  }
  float sch[4];
  #pragma unroll
  for(int h2=0;h2<4;h2++){
    float4 wv = *(const float4*)&w[h2][k*4];
    sch[h2] = v.x*wv.x + v.y*wv.y + v.z*wv.z + v.w*wv.w;
  }
  #pragma unroll
  for(int o=16;o>0;o>>=1){
    #pragma unroll
    for(int h2=0;h2<4;h2++) sch[h2] += __shfl_down(sch[h2], o, 32);
  }
  if(k==0) ((float4*)scores)[n] = make_float4(sch[0],sch[1],sch[2],sch[3]);
}

// ---------- per-graph softmax + keep select from scores ----------
__global__ __launch_bounds__(256) void k_poolsel(const float* __restrict__ scores,
    float minscore, float* __restrict__ sm4, unsigned char* __restrict__ keep,
    int* __restrict__ cnt, int* __restrict__ wl){
  __shared__ float red[4];
  const int t = threadIdx.x, g = blockIdx.x, n = g*256 + t;
  float4 s4 = ((const float4*)scores)[n];
  float scv[4] = {s4.x, s4.y, s4.z, s4.w};
  float4 smout;
  unsigned kb = 0;
  #pragma unroll 1
  for(int h=0;h<4;h++){
    float m = blockMax4(scv[h], red);
    float e = expf(scv[h]-m);
    float ssum = blockSum4(e, red);
    float sm = e/(ssum + 1e-16f);
    float smax = blockMax4(sm, red);
    float thr = fminf(smax - 1e-7f, minscore);
    ((float*)&smout)[h] = sm;
    if(sm > thr){
      kb |= (1u<<h);
      int p = atomicAdd(cnt, 1);
      wl[p] = (h<<16) | n;
    }
  }
  __syncthreads();
  ((float4*)sm4)[n] = smout;
  keep[n] = (unsigned char)kb;
}

// ---------- block-layer GraphConv(max) on kept (head,node) items ----------
__global__ __launch_bounds__(256) void k_blockconv(const float* __restrict__ cur,
    const int* __restrict__ offs, const int* __restrict__ csr,
    const unsigned char* __restrict__ keep, const float* __restrict__ sm4,
    const int* __restrict__ cnt, const int* __restrict__ wl,
    const float* __restrict__ Wrel, const float* __restrict__ Wroot,
    const float* __restrict__ bias,
    float* __restrict__ onew, float* __restrict__ bnsum, float* __restrict__ bnsq,
    const float* __restrict__ bns0, const float* __restrict__ bnq0,
    const float* __restrict__ g0, const float* __restrict__ b0bn, int fold){
  __shared__ __align__(16) float aggs[8][128];
  __shared__ __align__(16) float xps[8][128];
  __shared__ __align__(16) float scv[128];
  __shared__ __align__(16) float ofv[128];
  const int t = threadIdx.x, grp = t>>5, lane = t&31;
  if(t<128){
    float sv = 1.f, ov = 0.f;
    if(fold){
      float mu = bns0[t]*(1.0f/NN);
      float var = bnq0[t]*(1.0f/NN) - mu*mu;
      sv = g0[t]*rsqrtf(var+1e-5f);
      ov = b0bn[t] - mu*sv;
    }
    scv[t]=sv; ofv[t]=ov;
  }
  __syncthreads();
  const float4 s4l = *(const float4*)&scv[lane*4];
  const float4 o4l = *(const float4*)&ofv[lane*4];
  const int total = *cnt;
  for(int item = blockIdx.x*8 + grp; item < total; item += gridDim.x*8){
    const int wv = wl[item];
    const int h = wv>>16, n = wv & 0xFFFF;
    const float smn = sm4[n*4+h];
    const int e0 = offs[n], e1 = offs[n+1];
    float4 acc = make_float4(-INFINITY,-INFINITY,-INFINITY,-INFINITY);
    bool any = false;
    for(int e=e0;e<e1;e++){
      int s = csr[e];
      if((keep[s]>>h)&1){
        any = true;
        float sv = sm4[s*4+h];
        float4 v = ((const float4*)cur)[s*32 + lane];
        v.x = (v.x*s4l.x + o4l.x)*sv; v.y = (v.y*s4l.y + o4l.y)*sv;
        v.z = (v.z*s4l.z + o4l.z)*sv; v.w = (v.w*s4l.w + o4l.w)*sv;
        acc.x = fmaxf(acc.x, v.x); acc.y = fmaxf(acc.y, v.y);
        acc.z = fmaxf(acc.z, v.z); acc.w = fmaxf(acc.w, v.w);
      }
    }
    if(!any) acc = make_float4(0.f,0.f,0.f,0.f);
    *(float4*)&aggs[grp][lane*4] = acc;
    float4 xv = ((const float4*)cur)[n*32 + lane];
    xv.x = (xv.x*s4l.x + o4l.x)*smn; xv.y = (xv.y*s4l.y + o4l.y)*smn;
    xv.z = (xv.z*s4l.z + o4l.z)*smn; xv.w = (xv.w*s4l.w + o4l.w)*smn;
    *(float4*)&xps[grp][lane*4] = xv;
    // half-wave group: LDS write->read is program-ordered within the wave
    const float* Wr = Wrel  + (size_t)(h*32+lane)*128;
    const float* Wo = Wroot + (size_t)(h*32+lane)*128;
    float o = bias[h*32+lane];
    for(int k=0;k<32;k++){
      float4 a  = *(const float4*)&aggs[grp][k*4];
      float4 xx = *(const float4*)&xps[grp][k*4];
      float4 wr = ((const float4*)Wr)[k];
      float4 wo = ((const float4*)Wo)[k];
      o += a.x*wr.x + a.y*wr.y + a.z*wr.z + a.w*wr.w;
      o += xx.x*wo.x + xx.y*wo.y + xx.z*wo.z + xx.w*wo.w;
    }
    o = lrelu(o);
    onew[(size_t)n*128 + h*32 + lane] = o;
    atomicAdd(&bnsum[h*32+lane], o);
    atomicAdd(&bnsq[h*32+lane], o*o);
  }
}

// ---------- classification: one block per (graph, class) ----------
__global__ __launch_bounds__(256) void k_cls2(const float* __restrict__ cur,
    const float* __restrict__ scores,
    const float* __restrict__ gW1, const float* __restrict__ gb1,
    const float* __restrict__ gW2, const float* __restrict__ gb2,
    const float* __restrict__ fW1, const float* __restrict__ fb1,
    const float* __restrict__ fW2, const float* __restrict__ fb2,
    float* __restrict__ yws){
  __shared__ float red[4];
  __shared__ int keptL[256];
  __shared__ float keptS[256];
  __shared__ float gateL[256];
  __shared__ __align__(16) float xk[128];
  __shared__ __align__(16) float pooled[128];
  __shared__ int nkept;
  const int t = threadIdx.x;
  const int g = blockIdx.x >> 2, c = blockIdx.x & 3;
  const int n = g*256 + t;
  float sc = scores[n*4 + c];
  float m = blockMax4(sc, red);
  float e = expf(sc-m);
  float ssum = blockSum4(e, red);
  float sm = e/(ssum+1e-16f);
  float smax = blockMax4(sm, red);
  float thr = fminf(smax - 1e-7f, 0.8f);
  if(t==0) nkept = 0;
  __syncthreads();
  if(sm > thr){
    int p = atomicAdd(&nkept,1);
    keptL[p]=t; keptS[p]=sm;
  }
  __syncthreads();
  const int K = nkept;
  for(int k=0;k<K;k++){
    int ln = keptL[k]; float sv = keptS[k];
    if(t<32){
      float4 v = ((const float4*)(cur + (size_t)(g*256+ln)*128))[t];
      v.x*=sv; v.y*=sv; v.z*=sv; v.w*=sv;
      *(float4*)&xk[t*4] = v;
    }
    __syncthreads();
    float part = 0.f;
    if(t<128){
      const float* W = gW1 + (size_t)c*16384 + (size_t)t*128;
      float a = gb1[c*128+t];
      for(int f=0;f<32;f++){
        float4 xv = *(const float4*)&xk[f*4];
        float4 wv = ((const float4*)W)[f];
        a += xv.x*wv.x + xv.y*wv.y + xv.z*wv.z + xv.w*wv.w;
      }
      part = lrelu(a) * gW2[c*128+t];
    }
    float gs = blockSum4(part, red);
    if(t==0) gateL[k] = gs + gb2[c];
    __syncthreads();
  }
  float gv = (t<K)? gateL[t] : -INFINITY;
  float gm = blockMax4(gv, red);
  float ge = (t<K)? expf(gv-gm) : 0.f;
  float gsum = blockSum4(ge, red);
  if(t<K) gateL[t] = ge/(gsum+1e-16f);
  __syncthreads();
  if(t<128){
    float acc = 0.f;
    for(int k=0;k<K;k++)
      acc += gateL[k]*keptS[k]*cur[(size_t)(g*256+keptL[k])*128 + t];
    pooled[t]=acc;
  }
  __syncthreads();
  float part2=0.f;
  if(t<128){
    const float* F = fW1 + (size_t)c*16384 + (size_t)t*128;
    float a = fb1[c*128+t];
    for(int f=0;f<32;f++){
      float4 xv = *(const float4*)&pooled[f*4];
      float4 wv = ((const float4*)F)[f];
      a += xv.x*wv.x + xv.y*wv.y + xv.z*wv.z + xv.w*wv.w;
    }
    part2 = lrelu(a) * fW2[c*128+t];
  }
  float ysum = blockSum4(part2, red);
  if(t==0) yws[g*4+c] = ysum + fb2[c];
}

// ---------- final per-graph log_softmax over 4 class logits ----------
__global__ __launch_bounds__(256) void k_clsfin(const float* __restrict__ yws,
                                                float* __restrict__ out){
  const int g = threadIdx.x;            // single block, thread = graph
  float4 y = ((const float4*)yws)[g];
  float m = fmaxf(fmaxf(y.x,y.y), fmaxf(y.z,y.w));
  float l = logf(expf(y.x-m)+expf(y.y-m)+expf(y.z-m)+expf(y.w-m));
  float4 o = make_float4(y.x-m-l, y.y-m-l, y.z-m-l, y.w-m-l);
  ((float4*)out)[g] = o;
}

extern "C" void kernel_launch(void* const* d_in, const int* in_sizes, int n_in,
                              void* d_out, int out_size, void* d_ws, size_t ws_size,
                              hipStream_t stream){
  (void)in_sizes; (void)n_in; (void)out_size; (void)ws_size;
  const float* x     = (const float*)d_in[0];
  const int*   ei    = (const int*)d_in[1];
  const float* Wrel0 = (const float*)d_in[3];
  const float* Wroot0= (const float*)d_in[4];
  const float* b0    = (const float*)d_in[5];
  const float* bn0g  = (const float*)d_in[6];
  const float* bn0b  = (const float*)d_in[7];
  const float* bpw   = (const float*)d_in[8];
  const float* bWrel = (const float*)d_in[9];
  const float* bWroot= (const float*)d_in[10];
  const float* bbv   = (const float*)d_in[11];
  const float* bbng  = (const float*)d_in[12];
  const float* bbnb  = (const float*)d_in[13];
  const float* cpw   = (const float*)d_in[14];
  const float* gW1   = (const float*)d_in[15];
  const float* gb1   = (const float*)d_in[16];
  const float* gW2   = (const float*)d_in[17];
  const float* gb2   = (const float*)d_in[18];
  const float* fW1   = (const float*)d_in[19];
  const float* fb1   = (const float*)d_in[20];
  const float* fW2   = (const float*)d_in[21];
  const float* fb2   = (const float*)d_in[22];

  char* ws = (char*)d_ws;
  float* cur   = (float*)(ws + 0);                 // 33.55 MB
  float* onew  = (float*)(ws + 33554432ull);       // 33.55 MB (agg0 aliases it)
  float* agg0  = onew;
  int*   csr   = (int*)(ws + 67108864ull);         // 2 MB
  float* sm4   = (float*)(ws + 69206016ull);       // 1 MB (scores aliases it)
  float* scores= sm4;
  int*   wl    = (int*)(ws + 70254592ull);         // 1 MB
  int*   offs  = (int*)(ws + 71303168ull);         // 256 KB + pad
  int*   cursor= (int*)(ws + 71565568ull);         // 256 KB
  unsigned char* keep = (unsigned char*)(ws + 71827712ull); // 64 KB
  char*  Z     = ws + 71893248ull;                 // zero-init region
  int*   deg   = (int*)Z;
  float* bnsum0= (float*)(Z + 262144);
  float* bnsq0 = (float*)(Z + 262656);
  float* bnA   = (float*)(Z + 263168);
  float* bqA   = (float*)(Z + 263680);
  float* bnB   = (float*)(Z + 264192);
  float* bqB   = (float*)(Z + 264704);
  int*   cnt0  = (int*)(Z + 265216);
  int*   cnt1  = (int*)(Z + 265220);
  float* yws   = (float*)(Z + 266240);             // 4 KB, written before read

  hipMemsetAsync(Z, 0, 265224, stream);

  // CSR by dst
  k_count  <<<2048,256,0,stream>>>(ei, deg);
  k_scan   <<<1,1024,0,stream>>>(deg, offs, cursor);
  k_scatter<<<2048,256,0,stream>>>(ei, cursor, csr);

  // conv0 -> lrelu (+ fused bn0 stats; bn0 apply folded into consumers)
  k_agg0    <<<4096,256,0,stream>>>(x, offs, csr, agg0);
  k_conv0mm <<<1024,256,0,stream>>>(agg0, x, Wrel0, Wroot0, b0, cur, bnsum0, bnsq0);

  // pool layer 0: streamed scores (bn0-scale folded) + per-graph select
  k_stream<0><<<8192,256,0,stream>>>(cur, onew, keep, bnA, bqA, bbng, bbnb,
                                     bnsum0, bnsq0, bn0g, bn0b, bpw, scores);
  k_poolsel<<<256,256,0,stream>>>(scores, 0.7f, sm4, keep, cnt0, wl);

  // block layer 0 (bn0 folded into gathered rows)
  k_blockconv<<<256,256,0,stream>>>(cur, offs, csr, keep, sm4, cnt0, wl,
                                    bWrel, bWroot, bbv, onew, bnA, bqA,
                                    bnsum0, bnsq0, bn0g, bn0b, 1);

  // update layer 0 (materializes cur) + streamed scores for pool layer 1
  k_stream<1><<<8192,256,0,stream>>>(cur, onew, keep, bnA, bqA, bbng, bbnb,
                                     bnsum0, bnsq0, bn0g, bn0b, bpw + 512, scores);
  k_poolsel<<<256,256,0,stream>>>(scores, 0.7f, sm4, keep, cnt1, wl);

  // block layer 1 (no fold)
  k_blockconv<<<256,256,0,stream>>>(cur, offs, csr, keep, sm4, cnt1, wl,
                                    bWrel + 16384, bWroot + 16384, bbv + 128, onew, bnB, bqB,
                                    bnsum0, bnsq0, bn0g, bn0b, 0);

  // update layer 1 + streamed cls pool scores
  k_stream<2><<<8192,256,0,stream>>>(cur, onew, keep, bnB, bqB, bbng + 128, bbnb + 128,
                                     bnsum0, bnsq0, bn0g, bn0b, cpw, scores);

  // classification heads: block per (graph, class), then 4-way log_softmax
  k_cls2<<<1024,256,0,stream>>>(cur, scores, gW1, gb1, gW2, gb2,
                                fW1, fb1, fW2, fb2, yws);
  k_clsfin<<<1,256,0,stream>>>(yws, (float*)d_out);
}

// Round 7
// 430.771 us; speedup vs baseline: 1.1224x; 1.1224x over previous
//
#include <hip/hip_runtime.h>
#include <math.h>

#define NN 65536      // nodes
#define NE 524288     // edges
#define NG 256        // graphs (256 contiguous nodes each)
#define SLOPE 0.01f

__device__ __forceinline__ float lrelu(float v){ return v > 0.f ? v : SLOPE*v; }

// ---------- block reductions (256-thread blocks = 4 waves) ----------
__device__ __forceinline__ float blockMax4(float v, float* s4){
  #pragma unroll
  for(int o=32;o>0;o>>=1) v = fmaxf(v, __shfl_down(v, o, 64));
  int t = threadIdx.x;
  __syncthreads();
  if((t&63)==0) s4[t>>6] = v;
  __syncthreads();
  return fmaxf(fmaxf(s4[0], s4[1]), fmaxf(s4[2], s4[3]));
}
__device__ __forceinline__ float blockSum4(float v, float* s4){
  #pragma unroll
  for(int o=32;o>0;o>>=1) v += __shfl_down(v, o, 64);
  int t = threadIdx.x;
  __syncthreads();
  if((t&63)==0) s4[t>>6] = v;
  __syncthreads();
  return (s4[0]+s4[1])+(s4[2]+s4[3]);
}

// ---------- CSR build (by dst) ----------
__global__ __launch_bounds__(256) void k_count(const int* __restrict__ ei, int* __restrict__ deg){
  int e = blockIdx.x*256 + threadIdx.x;
  if(e < NE) atomicAdd(&deg[ei[NE + e]], 1);
}

__global__ __launch_bounds__(1024) void k_scan(const int* __restrict__ deg,
      int* __restrict__ offs, int* __restrict__ cursor){
  __shared__ int part[1024];
  int t = threadIdx.x;
  const int4* d4 = (const int4*)(deg + t*64);
  int4 buf[16];
  int s=0;
  #pragma unroll
  for(int i=0;i<16;i++){ buf[i]=d4[i]; s += buf[i].x+buf[i].y+buf[i].z+buf[i].w; }
  part[t]=s;
  __syncthreads();
  for(int off=1; off<1024; off<<=1){
    int v = (t>=off)? part[t-off] : 0;
    __syncthreads();
    part[t] += v;
    __syncthreads();
  }
  int run = (t==0)? 0 : part[t-1];
  #pragma unroll
  for(int i=0;i<16;i++){
    int4 d = buf[i];
    int4 o;
    o.x = run; run += d.x;
    o.y = run; run += d.y;
    o.z = run; run += d.z;
    o.w = run; run += d.w;
    ((int4*)(offs + t*64))[i] = o;
    ((int4*)(cursor + t*64))[i] = o;
  }
  if(t==1023) offs[NN] = run;
}

__global__ __launch_bounds__(256) void k_scatter(const int* __restrict__ ei,
      int* __restrict__ cursor, int* __restrict__ csr){
  int e = blockIdx.x*256 + threadIdx.x;
  if(e < NE){
    int d = ei[NE + e];
    int p = atomicAdd(&cursor[d], 1);
    csr[p] = ei[e];
  }
}

// ---------- conv0: agg[i] = max over in-edges of x[src], else 0 ----------
__global__ __launch_bounds__(256) void k_agg0(const float* __restrict__ x,
    const int* __restrict__ offs, const int* __restrict__ csr, float* __restrict__ agg0){
  int tid = blockIdx.x*256 + threadIdx.x;
  int node = tid>>4, q = tid&15;        // 16 threads (float4 lanes) per node
  int e0 = offs[node], e1 = offs[node+1];
  float4 acc = make_float4(0.f,0.f,0.f,0.f);
  if(e0 < e1){
    acc = make_float4(-INFINITY,-INFINITY,-INFINITY,-INFINITY);
    int e = e0;
    for(; e+7 < e1; e += 8){            // 8 independent gathers in flight
      int si[8];
      #pragma unroll
      for(int u=0;u<8;u++) si[u] = csr[e+u];
      float4 v[8];
      #pragma unroll
      for(int u=0;u<8;u++) v[u] = ((const float4*)x)[si[u]*16 + q];
      #pragma unroll
      for(int u=0;u<8;u++){
        acc.x=fmaxf(acc.x,v[u].x); acc.y=fmaxf(acc.y,v[u].y);
        acc.z=fmaxf(acc.z,v[u].z); acc.w=fmaxf(acc.w,v[u].w);
      }
    }
    for(; e < e1; e++){
      int s0 = csr[e];
      float4 v0 = ((const float4*)x)[s0*16 + q];
      acc.x=fmaxf(acc.x,v0.x); acc.y=fmaxf(acc.y,v0.y);
      acc.z=fmaxf(acc.z,v0.z); acc.w=fmaxf(acc.w,v0.w);
    }
  }
  ((float4*)agg0)[node*16 + q] = acc;
}

// ---------- conv0 matmul: cur = lrelu([agg0|x] @ [Wrel|Wroot]^T + b0) ----------
// 128x128 tile, 8x8 microtile, XOR-swizzled LDS (conflict-free b128 reads).
// amdgpu_waves_per_eu(1,2): cap occupancy target at 2 waves/EU so the RA keeps
// the 64-float acc + 16-float4 fragments in VGPRs instead of chasing occupancy
// and spilling (r3-r5: 88 VGPR + 16 MB spill; r2/r6 scalar: 80 VGPR + spill).
__global__ __launch_bounds__(256)
__attribute__((amdgpu_waves_per_eu(1,2)))
void k_conv0mm(
    const float* __restrict__ agg0, const float* __restrict__ x,
    const float* __restrict__ Wrel, const float* __restrict__ Wroot,
    const float* __restrict__ b0, float* __restrict__ cur,
    float* __restrict__ bnsum, float* __restrict__ bnsq){
  __shared__ float4 As[2048];   // 32 KB
  __shared__ float4 Ws[2048];   // 32 KB
  const int t = threadIdx.x;
  const int tn = t & 15;
  const int tc = t >> 4;
  float acc[8][8];
  #pragma unroll
  for(int i=0;i<8;i++)
    #pragma unroll
    for(int j=0;j<8;j++) acc[i][j]=0.f;

  const size_t tileoff = (size_t)blockIdx.x * 8192;
  #pragma unroll 1
  for(int ch=0; ch<2; ch++){
    const float4* gA = (const float4*)((ch==0? agg0 : x) + tileoff);
    const float4* gW = (const float4*)(ch==0? Wrel : Wroot);
    __syncthreads();
    #pragma unroll
    for(int i=0;i<8;i++){
      int idx = t + i*256;
      int n = idx>>4, k4 = idx&15;
      int sw = n*16 + ((k4 + (n>>3))&15);
      As[sw] = gA[idx];
      Ws[sw] = gW[idx];
    }
    __syncthreads();
    #pragma unroll 4
    for(int k4=0;k4<16;k4++){
      float4 a4[8], w4[8];
      #pragma unroll
      for(int i=0;i<8;i++) a4[i] = As[(tn*8+i)*16 + ((k4+tn)&15)];
      #pragma unroll
      for(int i=0;i<8;i++) w4[i] = Ws[(tc*8+i)*16 + ((k4+tc)&15)];
      #pragma unroll
      for(int i=0;i<8;i++)
        #pragma unroll
        for(int j=0;j<8;j++){
          acc[i][j] = fmaf(a4[i].x, w4[j].x, acc[i][j]);
          acc[i][j] = fmaf(a4[i].y, w4[j].y, acc[i][j]);
          acc[i][j] = fmaf(a4[i].z, w4[j].z, acc[i][j]);
          acc[i][j] = fmaf(a4[i].w, w4[j].w, acc[i][j]);
        }
    }
  }

  float bj[8];
  #pragma unroll
  for(int j=0;j<8;j++) bj[j] = b0[tc*8+j];
  float cs[8], cq[8];
  #pragma unroll
  for(int j=0;j<8;j++){ cs[j]=0.f; cq[j]=0.f; }
  const int nbase = blockIdx.x*128;
  #pragma unroll
  for(int i=0;i<8;i++){
    int node = nbase + tn*8 + i;
    float v[8];
    #pragma unroll
    for(int j=0;j<8;j++){
      v[j] = lrelu(acc[i][j] + bj[j]);
      cs[j] += v[j]; cq[j] += v[j]*v[j];
    }
    float4 o0 = make_float4(v[0],v[1],v[2],v[3]);
    float4 o1 = make_float4(v[4],v[5],v[6],v[7]);
    ((float4*)cur)[node*32 + tc*2 + 0] = o0;
    ((float4*)cur)[node*32 + tc*2 + 1] = o1;
  }
  __syncthreads();
  float* reds = (float*)As;
  float* redq = (float*)Ws;
  #pragma unroll
  for(int j=0;j<8;j++){
    reds[(tc*8+j)*16 + tn] = cs[j];
    redq[(tc*8+j)*16 + tn] = cq[j];
  }
  __syncthreads();
  if(t<128){
    float S=0.f, Q=0.f;
    #pragma unroll
    for(int i=0;i<16;i++){ S += reds[t*16+i]; Q += redq[t*16+i]; }
    atomicAdd(&bnsum[t], S);
    atomicAdd(&bnsq[t], Q);
  }
}

// ---------- streaming update + per-node pool scores ----------
template<int MODE>
__global__ __launch_bounds__(256) void k_stream(
    float* __restrict__ cur, const float* __restrict__ onew,
    const unsigned char* __restrict__ keepin,
    const float* __restrict__ bnsA, const float* __restrict__ bnqA,
    const float* __restrict__ g1, const float* __restrict__ b1,
    const float* __restrict__ bns0, const float* __restrict__ bnq0,
    const float* __restrict__ g0, const float* __restrict__ b0bn,
    const float* __restrict__ pw, float* __restrict__ scores){
  __shared__ __align__(16) float w[4][128];
  __shared__ __align__(16) float sc1[128], of1[128], sc0[128], of0[128];
  const int t = threadIdx.x;
  if(t<128){
    if(MODE>=1){
      float mu = bnsA[t]*(1.0f/NN);
      float var = bnqA[t]*(1.0f/NN) - mu*mu;
      float s = g1[t]*rsqrtf(var+1e-5f);
      sc1[t]=s; of1[t]=b1[t]-mu*s;
    }
    if(MODE<=1){
      float mu0 = bns0[t]*(1.0f/NN);
      float var0 = bnq0[t]*(1.0f/NN) - mu0*mu0;
      float s0 = g0[t]*rsqrtf(var0+1e-5f);
      sc0[t]=s0; of0[t]=b0bn[t]-mu0*s0;
    }
  }
  __syncthreads();
  for(int i=t;i<512;i+=256){
    float wv = pw[i];
    if(MODE==0) wv *= sc0[i&127];
    w[i>>7][i&127]=wv;
  }
  __syncthreads();
  const int tid = blockIdx.x*256 + t;
  const int n = tid>>5, k = tid&31;
  float4 v = ((const float4*)cur)[tid];
  if(MODE>=1){
    const int h = k>>3;
    float4 nv = make_float4(0.f,0.f,0.f,0.f);
    if((keepin[n]>>h)&1) nv = ((const float4*)onew)[tid];
    float4 s1 = *(const float4*)&sc1[k*4];
    float4 o1 = *(const float4*)&of1[k*4];
    if(MODE==1){
      float4 s0 = *(const float4*)&sc0[k*4];
      float4 o0 = *(const float4*)&of0[k*4];
      v.x = 0.5f*(s0.x*v.x+o0.x) + 0.25f*(s1.x*nv.x+o1.x);
      v.y = 0.5f*(s0.y*v.y+o0.y) + 0.25f*(s1.y*nv.y+o1.y);
      v.z = 0.5f*(s0.z*v.z+o0.z) + 0.25f*(s1.z*nv.z+o1.z);
      v.w = 0.5f*(s0.w*v.w+o0.w) + 0.25f*(s1.w*nv.w+o1.w);
    } else {
      v.x = 0.5f*v.x + 0.25f*(s1.x*nv.x+o1.x);
      v.y = 0.5f*v.y + 0.25f*(s1.y*nv.y+o1.y);
      v.z = 0.5f*v.z + 0.25f*(s1.z*nv.z+o1.z);
      v.w = 0.5f*v.w + 0.25f*(s1.w*nv.w+o1.w);
    }
    ((float4*)cur)[tid] = v;
  }
  float sch[4];
  #pragma unroll
  for(int h2=0;h2<4;h2++){
    float4 wv = *(const float4*)&w[h2][k*4];
    sch[h2] = v.x*wv.x + v.y*wv.y + v.z*wv.z + v.w*wv.w;
  }
  #pragma unroll
  for(int o=16;o>0;o>>=1){
    #pragma unroll
    for(int h2=0;h2<4;h2++) sch[h2] += __shfl_down(sch[h2], o, 32);
  }
  if(k==0) ((float4*)scores)[n] = make_float4(sch[0],sch[1],sch[2],sch[3]);
}

// ---------- per-graph softmax + keep select from scores ----------
__global__ __launch_bounds__(256) void k_poolsel(const float* __restrict__ scores,
    float minscore, float* __restrict__ sm4, unsigned char* __restrict__ keep,
    int* __restrict__ cnt, int* __restrict__ wl){
  __shared__ float red[4];
  const int t = threadIdx.x, g = blockIdx.x, n = g*256 + t;
  float4 s4 = ((const float4*)scores)[n];
  float scv[4] = {s4.x, s4.y, s4.z, s4.w};
  float4 smout;
  unsigned kb = 0;
  #pragma unroll 1
  for(int h=0;h<4;h++){
    float m = blockMax4(scv[h], red);
    float e = expf(scv[h]-m);
    float ssum = blockSum4(e, red);
    float sm = e/(ssum + 1e-16f);
    float smax = blockMax4(sm, red);
    float thr = fminf(smax - 1e-7f, minscore);
    ((float*)&smout)[h] = sm;
    if(sm > thr){
      kb |= (1u<<h);
      int p = atomicAdd(cnt, 1);
      wl[p] = (h<<16) | n;
    }
  }
  __syncthreads();
  ((float4*)sm4)[n] = smout;
  keep[n] = (unsigned char)kb;
}

// ---------- block-layer GraphConv(max) on kept (head,node) items ----------
__global__ __launch_bounds__(256) void k_blockconv(const float* __restrict__ cur,
    const int* __restrict__ offs, const int* __restrict__ csr,
    const unsigned char* __restrict__ keep, const float* __restrict__ sm4,
    const int* __restrict__ cnt, const int* __restrict__ wl,
    const float* __restrict__ Wrel, const float* __restrict__ Wroot,
    const float* __restrict__ bias,
    float* __restrict__ onew, float* __restrict__ bnsum, float* __restrict__ bnsq,
    const float* __restrict__ bns0, const float* __restrict__ bnq0,
    const float* __restrict__ g0, const float* __restrict__ b0bn, int fold){
  __shared__ __align__(16) float aggs[8][128];
  __shared__ __align__(16) float xps[8][128];
  __shared__ __align__(16) float scv[128];
  __shared__ __align__(16) float ofv[128];
  const int t = threadIdx.x, grp = t>>5, lane = t&31;
  if(t<128){
    float sv = 1.f, ov = 0.f;
    if(fold){
      float mu = bns0[t]*(1.0f/NN);
      float var = bnq0[t]*(1.0f/NN) - mu*mu;
      sv = g0[t]*rsqrtf(var+1e-5f);
      ov = b0bn[t] - mu*sv;
    }
    scv[t]=sv; ofv[t]=ov;
  }
  __syncthreads();
  const float4 s4l = *(const float4*)&scv[lane*4];
  const float4 o4l = *(const float4*)&ofv[lane*4];
  const int total = *cnt;
  for(int item = blockIdx.x*8 + grp; item < total; item += gridDim.x*8){
    const int wv = wl[item];
    const int h = wv>>16, n = wv & 0xFFFF;
    const float smn = sm4[n*4+h];
    const int e0 = offs[n], e1 = offs[n+1];
    float4 acc = make_float4(-INFINITY,-INFINITY,-INFINITY,-INFINITY);
    bool any = false;
    for(int e=e0;e<e1;e++){
      int s = csr[e];
      if((keep[s]>>h)&1){
        any = true;
        float sv = sm4[s*4+h];
        float4 v = ((const float4*)cur)[s*32 + lane];
        v.x = (v.x*s4l.x + o4l.x)*sv; v.y = (v.y*s4l.y + o4l.y)*sv;
        v.z = (v.z*s4l.z + o4l.z)*sv; v.w = (v.w*s4l.w + o4l.w)*sv;
        acc.x = fmaxf(acc.x, v.x); acc.y = fmaxf(acc.y, v.y);
        acc.z = fmaxf(acc.z, v.z); acc.w = fmaxf(acc.w, v.w);
      }
    }
    if(!any) acc = make_float4(0.f,0.f,0.f,0.f);
    *(float4*)&aggs[grp][lane*4] = acc;
    float4 xv = ((const float4*)cur)[n*32 + lane];
    xv.x = (xv.x*s4l.x + o4l.x)*smn; xv.y = (xv.y*s4l.y + o4l.y)*smn;
    xv.z = (xv.z*s4l.z + o4l.z)*smn; xv.w = (xv.w*s4l.w + o4l.w)*smn;
    *(float4*)&xps[grp][lane*4] = xv;
    // half-wave group: LDS write->read is program-ordered within the wave
    const float* Wr = Wrel  + (size_t)(h*32+lane)*128;
    const float* Wo = Wroot + (size_t)(h*32+lane)*128;
    float o = bias[h*32+lane];
    for(int k=0;k<32;k++){
      float4 a  = *(const float4*)&aggs[grp][k*4];
      float4 xx = *(const float4*)&xps[grp][k*4];
      float4 wr = ((const float4*)Wr)[k];
      float4 wo = ((const float4*)Wo)[k];
      o += a.x*wr.x + a.y*wr.y + a.z*wr.z + a.w*wr.w;
      o += xx.x*wo.x + xx.y*wo.y + xx.z*wo.z + xx.w*wo.w;
    }
    o = lrelu(o);
    onew[(size_t)n*128 + h*32 + lane] = o;
    atomicAdd(&bnsum[h*32+lane], o);
    atomicAdd(&bnsq[h*32+lane], o*o);
  }
}

// ---------- classification: one block per (graph, class) ----------
__global__ __launch_bounds__(256) void k_cls2(const float* __restrict__ cur,
    const float* __restrict__ scores,
    const float* __restrict__ gW1, const float* __restrict__ gb1,
    const float* __restrict__ gW2, const float* __restrict__ gb2,
    const float* __restrict__ fW1, const float* __restrict__ fb1,
    const float* __restrict__ fW2, const float* __restrict__ fb2,
    float* __restrict__ yws){
  __shared__ float red[4];
  __shared__ int keptL[256];
  __shared__ float keptS[256];
  __shared__ float gateL[256];
  __shared__ __align__(16) float xk[128];
  __shared__ __align__(16) float pooled[128];
  __shared__ int nkept;
  const int t = threadIdx.x;
  const int g = blockIdx.x >> 2, c = blockIdx.x & 3;
  const int n = g*256 + t;
  float sc = scores[n*4 + c];
  float m = blockMax4(sc, red);
  float e = expf(sc-m);
  float ssum = blockSum4(e, red);
  float sm = e/(ssum+1e-16f);
  float smax = blockMax4(sm, red);
  float thr = fminf(smax - 1e-7f, 0.8f);
  if(t==0) nkept = 0;
  __syncthreads();
  if(sm > thr){
    int p = atomicAdd(&nkept,1);
    keptL[p]=t; keptS[p]=sm;
  }
  __syncthreads();
  const int K = nkept;
  for(int k=0;k<K;k++){
    int ln = keptL[k]; float sv = keptS[k];
    if(t<32){
      float4 v = ((const float4*)(cur + (size_t)(g*256+ln)*128))[t];
      v.x*=sv; v.y*=sv; v.z*=sv; v.w*=sv;
      *(float4*)&xk[t*4] = v;
    }
    __syncthreads();
    float part = 0.f;
    if(t<128){
      const float* W = gW1 + (size_t)c*16384 + (size_t)t*128;
      float a = gb1[c*128+t];
      for(int f=0;f<32;f++){
        float4 xv = *(const float4*)&xk[f*4];
        float4 wv = ((const float4*)W)[f];
        a += xv.x*wv.x + xv.y*wv.y + xv.z*wv.z + xv.w*wv.w;
      }
      part = lrelu(a) * gW2[c*128+t];
    }
    float gs = blockSum4(part, red);
    if(t==0) gateL[k] = gs + gb2[c];
    __syncthreads();
  }
  float gv = (t<K)? gateL[t] : -INFINITY;
  float gm = blockMax4(gv, red);
  float ge = (t<K)? expf(gv-gm) : 0.f;
  float gsum = blockSum4(ge, red);
  if(t<K) gateL[t] = ge/(gsum+1e-16f);
  __syncthreads();
  if(t<128){
    float acc = 0.f;
    for(int k=0;k<K;k++)
      acc += gateL[k]*keptS[k]*cur[(size_t)(g*256+keptL[k])*128 + t];
    pooled[t]=acc;
  }
  __syncthreads();
  float part2=0.f;
  if(t<128){
    const float* F = fW1 + (size_t)c*16384 + (size_t)t*128;
    float a = fb1[c*128+t];
    for(int f=0;f<32;f++){
      float4 xv = *(const float4*)&pooled[f*4];
      float4 wv = ((const float4*)F)[f];
      a += xv.x*wv.x + xv.y*wv.y + xv.z*wv.z + xv.w*wv.w;
    }
    part2 = lrelu(a) * fW2[c*128+t];
  }
  float ysum = blockSum4(part2, red);
  if(t==0) yws[g*4+c] = ysum + fb2[c];
}

// ---------- final per-graph log_softmax over 4 class logits ----------
__global__ __launch_bounds__(256) void k_clsfin(const float* __restrict__ yws,
                                                float* __restrict__ out){
  const int g = threadIdx.x;            // single block, thread = graph
  float4 y = ((const float4*)yws)[g];
  float m = fmaxf(fmaxf(y.x,y.y), fmaxf(y.z,y.w));
  float l = logf(expf(y.x-m)+expf(y.y-m)+expf(y.z-m)+expf(y.w-m));
  float4 o = make_float4(y.x-m-l, y.y-m-l, y.z-m-l, y.w-m-l);
  ((float4*)out)[g] = o;
}

extern "C" void kernel_launch(void* const* d_in, const int* in_sizes, int n_in,
                              void* d_out, int out_size, void* d_ws, size_t ws_size,
                              hipStream_t stream){
  (void)in_sizes; (void)n_in; (void)out_size; (void)ws_size;
  const float* x     = (const float*)d_in[0];
  const int*   ei    = (const int*)d_in[1];
  const float* Wrel0 = (const float*)d_in[3];
  const float* Wroot0= (const float*)d_in[4];
  const float* b0    = (const float*)d_in[5];
  const float* bn0g  = (const float*)d_in[6];
  const float* bn0b  = (const float*)d_in[7];
  const float* bpw   = (const float*)d_in[8];
  const float* bWrel = (const float*)d_in[9];
  const float* bWroot= (const float*)d_in[10];
  const float* bbv   = (const float*)d_in[11];
  const float* bbng  = (const float*)d_in[12];
  const float* bbnb  = (const float*)d_in[13];
  const float* cpw   = (const float*)d_in[14];
  const float* gW1   = (const float*)d_in[15];
  const float* gb1   = (const float*)d_in[16];
  const float* gW2   = (const float*)d_in[17];
  const float* gb2   = (const float*)d_in[18];
  const float* fW1   = (const float*)d_in[19];
  const float* fb1   = (const float*)d_in[20];
  const float* fW2   = (const float*)d_in[21];
  const float* fb2   = (const float*)d_in[22];

  char* ws = (char*)d_ws;
  float* cur   = (float*)(ws + 0);                 // 33.55 MB
  float* onew  = (float*)(ws + 33554432ull);       // 33.55 MB (agg0 aliases it)
  float* agg0  = onew;
  int*   csr   = (int*)(ws + 67108864ull);         // 2 MB
  float* sm4   = (float*)(ws + 69206016ull);       // 1 MB (scores aliases it)
  float* scores= sm4;
  int*   wl    = (int*)(ws + 70254592ull);         // 1 MB
  int*   offs  = (int*)(ws + 71303168ull);         // 256 KB + pad
  int*   cursor= (int*)(ws + 71565568ull);         // 256 KB
  unsigned char* keep = (unsigned char*)(ws + 71827712ull); // 64 KB
  char*  Z     = ws + 71893248ull;                 // zero-init region
  int*   deg   = (int*)Z;
  float* bnsum0= (float*)(Z + 262144);
  float* bnsq0 = (float*)(Z + 262656);
  float* bnA   = (float*)(Z + 263168);
  float* bqA   = (float*)(Z + 263680);
  float* bnB   = (float*)(Z + 264192);
  float* bqB   = (float*)(Z + 264704);
  int*   cnt0  = (int*)(Z + 265216);
  int*   cnt1  = (int*)(Z + 265220);
  float* yws   = (float*)(Z + 266240);             // 4 KB, written before read

  hipMemsetAsync(Z, 0, 265224, stream);

  // CSR by dst
  k_count  <<<2048,256,0,stream>>>(ei, deg);
  k_scan   <<<1,1024,0,stream>>>(deg, offs, cursor);
  k_scatter<<<2048,256,0,stream>>>(ei, cursor, csr);

  // conv0 -> lrelu (+ fused bn0 stats; bn0 apply folded into consumers)
  k_agg0    <<<4096,256,0,stream>>>(x, offs, csr, agg0);
  k_conv0mm <<<512,256,0,stream>>>(agg0, x, Wrel0, Wroot0, b0, cur, bnsum0, bnsq0);

  // pool layer 0: streamed scores (bn0-scale folded) + per-graph select
  k_stream<0><<<8192,256,0,stream>>>(cur, onew, keep, bnA, bqA, bbng, bbnb,
                                     bnsum0, bnsq0, bn0g, bn0b, bpw, scores);
  k_poolsel<<<256,256,0,stream>>>(scores, 0.7f, sm4, keep, cnt0, wl);

  // block layer 0 (bn0 folded into gathered rows)
  k_blockconv<<<256,256,0,stream>>>(cur, offs, csr, keep, sm4, cnt0, wl,
                                    bWrel, bWroot, bbv, onew, bnA, bqA,
                                    bnsum0, bnsq0, bn0g, bn0b, 1);

  // update layer 0 (materializes cur) + streamed scores for pool layer 1
  k_stream<1><<<8192,256,0,stream>>>(cur, onew, keep, bnA, bqA, bbng, bbnb,
                                     bnsum0, bnsq0, bn0g, bn0b, bpw + 512, scores);
  k_poolsel<<<256,256,0,stream>>>(scores, 0.7f, sm4, keep, cnt1, wl);

  // block layer 1 (no fold)
  k_blockconv<<<256,256,0,stream>>>(cur, offs, csr, keep, sm4, cnt1, wl,
                                    bWrel + 16384, bWroot + 16384, bbv + 128, onew, bnB, bqB,
                                    bnsum0, bnsq0, bn0g, bn0b, 0);

  // update layer 1 + streamed cls pool scores
  k_stream<2><<<8192,256,0,stream>>>(cur, onew, keep, bnB, bqB, bbng + 128, bbnb + 128,
                                     bnsum0, bnsq0, bn0g, bn0b, cpw, scores);

  // classification heads: block per (graph, class), then 4-way log_softmax
  k_cls2<<<1024,256,0,stream>>>(cur, scores, gW1, gb1, gW2, gb2,
                                fW1, fb1, fW2, fb2, yws);
  k_clsfin<<<1,256,0,stream>>>(yws, (float*)d_out);
}

// Round 8
// 385.484 us; speedup vs baseline: 1.2542x; 1.1175x over previous
//
#include <hip/hip_runtime.h>
#include <math.h>

#define NN 65536      // nodes
#define NE 524288     // edges
#define NG 256        // graphs (256 contiguous nodes each)
#define SLOPE 0.01f
#define CAP 131072    // worklist capacity per layer (typ. ~1k items)

__device__ __forceinline__ float lrelu(float v){ return v > 0.f ? v : SLOPE*v; }

// ---------- block reductions (256-thread blocks = 4 waves) ----------
__device__ __forceinline__ float blockMax4(float v, float* s4){
  #pragma unroll
  for(int o=32;o>0;o>>=1) v = fmaxf(v, __shfl_down(v, o, 64));
  int t = threadIdx.x;
  __syncthreads();
  if((t&63)==0) s4[t>>6] = v;
  __syncthreads();
  return fmaxf(fmaxf(s4[0], s4[1]), fmaxf(s4[2], s4[3]));
}
__device__ __forceinline__ float blockSum4(float v, float* s4){
  #pragma unroll
  for(int o=32;o>0;o>>=1) v += __shfl_down(v, o, 64);
  int t = threadIdx.x;
  __syncthreads();
  if((t&63)==0) s4[t>>6] = v;
  __syncthreads();
  return (s4[0]+s4[1])+(s4[2]+s4[3]);
}

// ---------- CSR build (by dst) ----------
__global__ __launch_bounds__(256) void k_count(const int* __restrict__ ei, int* __restrict__ deg){
  int e = blockIdx.x*256 + threadIdx.x;
  if(e < NE) atomicAdd(&deg[ei[NE + e]], 1);
}

__global__ __launch_bounds__(1024) void k_scan(const int* __restrict__ deg,
      int* __restrict__ offs, int* __restrict__ cursor){
  __shared__ int part[1024];
  int t = threadIdx.x;
  const int4* d4 = (const int4*)(deg + t*64);
  int4 buf[16];
  int s=0;
  #pragma unroll
  for(int i=0;i<16;i++){ buf[i]=d4[i]; s += buf[i].x+buf[i].y+buf[i].z+buf[i].w; }
  part[t]=s;
  __syncthreads();
  for(int off=1; off<1024; off<<=1){
    int v = (t>=off)? part[t-off] : 0;
    __syncthreads();
    part[t] += v;
    __syncthreads();
  }
  int run = (t==0)? 0 : part[t-1];
  #pragma unroll
  for(int i=0;i<16;i++){
    int4 d = buf[i];
    int4 o;
    o.x = run; run += d.x;
    o.y = run; run += d.y;
    o.z = run; run += d.z;
    o.w = run; run += d.w;
    ((int4*)(offs + t*64))[i] = o;
    ((int4*)(cursor + t*64))[i] = o;
  }
  if(t==1023) offs[NN] = run;
}

__global__ __launch_bounds__(256) void k_scatter(const int* __restrict__ ei,
      int* __restrict__ cursor, int* __restrict__ csr){
  int e = blockIdx.x*256 + threadIdx.x;
  if(e < NE){
    int d = ei[NE + e];
    int p = atomicAdd(&cursor[d], 1);
    csr[p] = ei[e];
  }
}

// ---------- conv0: agg[i] = max over in-edges of x[src], else 0 ----------
__global__ __launch_bounds__(256) void k_agg0(const float* __restrict__ x,
    const int* __restrict__ offs, const int* __restrict__ csr, float* __restrict__ agg0){
  int tid = blockIdx.x*256 + threadIdx.x;
  int node = tid>>4, q = tid&15;
  int e0 = offs[node], e1 = offs[node+1];
  float4 acc = make_float4(0.f,0.f,0.f,0.f);
  if(e0 < e1){
    acc = make_float4(-INFINITY,-INFINITY,-INFINITY,-INFINITY);
    int e = e0;
    for(; e+7 < e1; e += 8){
      int si[8];
      #pragma unroll
      for(int u=0;u<8;u++) si[u] = csr[e+u];
      float4 v[8];
      #pragma unroll
      for(int u=0;u<8;u++) v[u] = ((const float4*)x)[si[u]*16 + q];
      #pragma unroll
      for(int u=0;u<8;u++){
        acc.x=fmaxf(acc.x,v[u].x); acc.y=fmaxf(acc.y,v[u].y);
        acc.z=fmaxf(acc.z,v[u].z); acc.w=fmaxf(acc.w,v[u].w);
      }
    }
    for(; e < e1; e++){
      int s0 = csr[e];
      float4 v0 = ((const float4*)x)[s0*16 + q];
      acc.x=fmaxf(acc.x,v0.x); acc.y=fmaxf(acc.y,v0.y);
      acc.z=fmaxf(acc.z,v0.z); acc.w=fmaxf(acc.w,v0.w);
    }
  }
  ((float4*)agg0)[node*16 + q] = acc;
}

// ---------- conv0 matmul: cur0 = lrelu([agg0|x] @ [Wrel|Wroot]^T + b0) ----------
__global__ __launch_bounds__(256, 2) void k_conv0mm(
    const float* __restrict__ agg0, const float* __restrict__ x,
    const float* __restrict__ Wrel, const float* __restrict__ Wroot,
    const float* __restrict__ b0, float* __restrict__ cur,
    float* __restrict__ bnsum, float* __restrict__ bnsq){
  __shared__ float4 As[2048];
  __shared__ float4 Ws[2048];
  const int t = threadIdx.x;
  const int tn = t & 15;
  const int tc = t >> 4;
  float acc[8][8];
  #pragma unroll
  for(int i=0;i<8;i++)
    #pragma unroll
    for(int j=0;j<8;j++) acc[i][j]=0.f;

  const size_t tileoff = (size_t)blockIdx.x * 8192;
  #pragma unroll 1
  for(int ch=0; ch<2; ch++){
    const float4* gA = (const float4*)((ch==0? agg0 : x) + tileoff);
    const float4* gW = (const float4*)(ch==0? Wrel : Wroot);
    __syncthreads();
    #pragma unroll
    for(int i=0;i<8;i++){
      int idx = t + i*256;
      int n = idx>>4, k4 = idx&15;
      int sw = n*16 + ((k4 + (n>>3))&15);
      As[sw] = gA[idx];
      Ws[sw] = gW[idx];
    }
    __syncthreads();
    #pragma unroll 4
    for(int k4=0;k4<16;k4++){
      float4 a4[8], w4[8];
      #pragma unroll
      for(int i=0;i<8;i++) a4[i] = As[(tn*8+i)*16 + ((k4+tn)&15)];
      #pragma unroll
      for(int i=0;i<8;i++) w4[i] = Ws[(tc*8+i)*16 + ((k4+tc)&15)];
      #pragma unroll
      for(int i=0;i<8;i++)
        #pragma unroll
        for(int j=0;j<8;j++){
          acc[i][j] = fmaf(a4[i].x, w4[j].x, acc[i][j]);
          acc[i][j] = fmaf(a4[i].y, w4[j].y, acc[i][j]);
          acc[i][j] = fmaf(a4[i].z, w4[j].z, acc[i][j]);
          acc[i][j] = fmaf(a4[i].w, w4[j].w, acc[i][j]);
        }
    }
  }

  float bj[8];
  #pragma unroll
  for(int j=0;j<8;j++) bj[j] = b0[tc*8+j];
  float cs[8], cq[8];
  #pragma unroll
  for(int j=0;j<8;j++){ cs[j]=0.f; cq[j]=0.f; }
  const int nbase = blockIdx.x*128;
  #pragma unroll
  for(int i=0;i<8;i++){
    int node = nbase + tn*8 + i;
    float v[8];
    #pragma unroll
    for(int j=0;j<8;j++){
      v[j] = lrelu(acc[i][j] + bj[j]);
      cs[j] += v[j]; cq[j] += v[j]*v[j];
    }
    float4 o0 = make_float4(v[0],v[1],v[2],v[3]);
    float4 o1 = make_float4(v[4],v[5],v[6],v[7]);
    ((float4*)cur)[node*32 + tc*2 + 0] = o0;
    ((float4*)cur)[node*32 + tc*2 + 1] = o1;
  }
  __syncthreads();
  float* reds = (float*)As;
  float* redq = (float*)Ws;
  #pragma unroll
  for(int j=0;j<8;j++){
    reds[(tc*8+j)*16 + tn] = cs[j];
    redq[(tc*8+j)*16 + tn] = cq[j];
  }
  __syncthreads();
  if(t<128){
    float S=0.f, Q=0.f;
    #pragma unroll
    for(int i=0;i<16;i++){ S += reds[t*16+i]; Q += redq[t*16+i]; }
    atomicAdd(&bnsum[t], S);
    atomicAdd(&bnsq[t], Q);
  }
}

// ---------- one pass over cur0: scores for pool0, pool1, cls (affine fold) ----------
// cur_L = alpha_L*cur0 + beta_L (+ sparse corr). Per-graph-constant terms cancel
// in the segment softmax, so: scores0 = cur0.(sc0*w0), pre1 = cur0.(0.5*sc0*w1),
// pre2 = cur0.(0.25*sc0*wcls). Sparse corrections patched later.
__global__ __launch_bounds__(256) void k_scores(const float* __restrict__ cur0,
    const float* __restrict__ bns0, const float* __restrict__ bnq0,
    const float* __restrict__ g0,
    const float* __restrict__ pw0, const float* __restrict__ pw1,
    const float* __restrict__ pwc,
    float* __restrict__ scores0, float* __restrict__ pre1, float* __restrict__ pre2){
  __shared__ __align__(16) float w[12][128];
  __shared__ float sc0s[128];
  const int t = threadIdx.x;
  if(t<128){
    float mu = bns0[t]*(1.0f/NN);
    float var = bnq0[t]*(1.0f/NN) - mu*mu;
    sc0s[t] = g0[t]*rsqrtf(var+1e-5f);
  }
  __syncthreads();
  for(int i=t;i<512;i+=256){
    int h=i>>7, j=i&127;
    float s = sc0s[j];
    w[h][j]   = pw0[i]*s;
    w[4+h][j] = pw1[i]*(0.5f*s);
    w[8+h][j] = pwc[i]*(0.25f*s);
  }
  __syncthreads();
  const int tid = blockIdx.x*256 + t;
  const int n = tid>>5, k = tid&31;
  float4 v = ((const float4*)cur0)[tid];
  float a[12];
  #pragma unroll
  for(int q=0;q<12;q++){
    float4 wv = *(const float4*)&w[q][k*4];
    a[q] = v.x*wv.x + v.y*wv.y + v.z*wv.z + v.w*wv.w;
  }
  #pragma unroll
  for(int o=16;o>0;o>>=1){
    #pragma unroll
    for(int q=0;q<12;q++) a[q] += __shfl_down(a[q], o, 32);
  }
  if(k==0){
    ((float4*)scores0)[n] = make_float4(a[0],a[1],a[2],a[3]);
    ((float4*)pre1)[n]    = make_float4(a[4],a[5],a[6],a[7]);
    ((float4*)pre2)[n]    = make_float4(a[8],a[9],a[10],a[11]);
  }
}

// ---------- pool select layer 0 (sm4 aliases scores: read-before-write) ----------
__global__ __launch_bounds__(256) void k_poolsel(const float* __restrict__ scores,
    float minscore, float* __restrict__ sm4, unsigned char* __restrict__ keep,
    int* __restrict__ cnt, int* __restrict__ wl, int* __restrict__ idx){
  __shared__ float red[4];
  const int t = threadIdx.x, g = blockIdx.x, n = g*256 + t;
  float4 s4 = ((const float4*)scores)[n];
  float scv[4] = {s4.x, s4.y, s4.z, s4.w};
  float4 smout;
  unsigned kb = 0;
  #pragma unroll 1
  for(int h=0;h<4;h++){
    float m = blockMax4(scv[h], red);
    float e = expf(scv[h]-m);
    float ssum = blockSum4(e, red);
    float sm = e/(ssum + 1e-16f);
    float smax = blockMax4(sm, red);
    float thr = fminf(smax - 1e-7f, minscore);
    ((float*)&smout)[h] = sm;
    if(sm > thr){
      int p = atomicAdd(cnt, 1);
      if(p < CAP){
        kb |= (1u<<h);
        wl[p] = (h<<16) | n;
        idx[n*4+h] = p;
      }
    }
  }
  __syncthreads();
  ((float4*)sm4)[n] = smout;
  keep[n] = (unsigned char)kb;
}

// ---------- layer-0 GraphConv(max) on kept items (rows = bn0(cur0)) ----------
__global__ __launch_bounds__(256) void k_blockconv0(const float* __restrict__ cur0,
    const int* __restrict__ offs, const int* __restrict__ csr,
    const unsigned char* __restrict__ keep, const float* __restrict__ sm4,
    const int* __restrict__ cnt, const int* __restrict__ wl,
    const float* __restrict__ Wrel, const float* __restrict__ Wroot,
    const float* __restrict__ bias,
    float* __restrict__ new1c, float* __restrict__ bnsum, float* __restrict__ bnsq,
    const float* __restrict__ bns0, const float* __restrict__ bnq0,
    const float* __restrict__ g0, const float* __restrict__ b0bn){
  __shared__ __align__(16) float aggs[8][128];
  __shared__ __align__(16) float xps[8][128];
  __shared__ __align__(16) float scv[128];
  __shared__ __align__(16) float ofv[128];
  const int t = threadIdx.x, grp = t>>5, lane = t&31;
  if(t<128){
    float mu = bns0[t]*(1.0f/NN);
    float var = bnq0[t]*(1.0f/NN) - mu*mu;
    float sv = g0[t]*rsqrtf(var+1e-5f);
    scv[t]=sv; ofv[t]=b0bn[t]-mu*sv;
  }
  __syncthreads();
  const float4 s4l = *(const float4*)&scv[lane*4];
  const float4 o4l = *(const float4*)&ofv[lane*4];
  int total = *cnt; if(total > CAP) total = CAP;
  for(int item = blockIdx.x*8 + grp; item < total; item += gridDim.x*8){
    const int wv = wl[item];
    const int h = wv>>16, n = wv & 0xFFFF;
    const float smn = sm4[n*4+h];
    const int e0 = offs[n], e1 = offs[n+1];
    float4 acc = make_float4(-INFINITY,-INFINITY,-INFINITY,-INFINITY);
    bool any = false;
    for(int e=e0;e<e1;e++){
      int s = csr[e];
      if((keep[s]>>h)&1){
        any = true;
        float sv = sm4[s*4+h];
        float4 v = ((const float4*)cur0)[s*32 + lane];
        v.x = (v.x*s4l.x + o4l.x)*sv; v.y = (v.y*s4l.y + o4l.y)*sv;
        v.z = (v.z*s4l.z + o4l.z)*sv; v.w = (v.w*s4l.w + o4l.w)*sv;
        acc.x = fmaxf(acc.x, v.x); acc.y = fmaxf(acc.y, v.y);
        acc.z = fmaxf(acc.z, v.z); acc.w = fmaxf(acc.w, v.w);
      }
    }
    if(!any) acc = make_float4(0.f,0.f,0.f,0.f);
    *(float4*)&aggs[grp][lane*4] = acc;
    float4 xv = ((const float4*)cur0)[n*32 + lane];
    xv.x = (xv.x*s4l.x + o4l.x)*smn; xv.y = (xv.y*s4l.y + o4l.y)*smn;
    xv.z = (xv.z*s4l.z + o4l.z)*smn; xv.w = (xv.w*s4l.w + o4l.w)*smn;
    *(float4*)&xps[grp][lane*4] = xv;
    // half-wave group: LDS write->read program-ordered within the wave
    const float* Wr = Wrel  + (size_t)(h*32+lane)*128;
    const float* Wo = Wroot + (size_t)(h*32+lane)*128;
    float o = bias[h*32+lane];
    for(int k=0;k<32;k++){
      float4 a  = *(const float4*)&aggs[grp][k*4];
      float4 xx = *(const float4*)&xps[grp][k*4];
      float4 wr = ((const float4*)Wr)[k];
      float4 wo = ((const float4*)Wo)[k];
      o += a.x*wr.x + a.y*wr.y + a.z*wr.z + a.w*wr.w;
      o += xx.x*wo.x + xx.y*wo.y + xx.z*wo.z + xx.w*wo.w;
    }
    o = lrelu(o);
    new1c[(size_t)item*32 + lane] = o;
    atomicAdd(&bnsum[h*32+lane], o);
    atomicAdd(&bnsq[h*32+lane], o*o);
  }
}

// ---------- pool select layer 1: patch pre1 (and pre2) with layer-1 corrections,
// then softmax/keep. sm4out aliases pre1 (read-before-write). ----------
__global__ __launch_bounds__(256) void k_poolsel1(
    const float* __restrict__ pre1, float* __restrict__ pre2,
    const int* __restrict__ cnt0, const int* __restrict__ wl0,
    const float* __restrict__ new1c,
    const float* __restrict__ bnsA, const float* __restrict__ bnqA,
    const float* __restrict__ g1v,
    const float* __restrict__ pw1, const float* __restrict__ pwc,
    float minscore, float* __restrict__ sm4out, unsigned char* __restrict__ keep1,
    int* __restrict__ cnt1, int* __restrict__ wl1, int* __restrict__ idx1){
  __shared__ float red[4];
  __shared__ float s1s[128];
  __shared__ __align__(16) float w1s[4][128];
  __shared__ __align__(16) float wcs[4][128];
  __shared__ float patch1[256][4];
  const int t = threadIdx.x, g = blockIdx.x;
  if(t<128){
    float mu = bnsA[t]*(1.0f/NN);
    float var = bnqA[t]*(1.0f/NN) - mu*mu;
    s1s[t] = g1v[t]*rsqrtf(var+1e-5f);
  }
  for(int i=t;i<512;i+=256){ w1s[i>>7][i&127]=pw1[i]; wcs[i>>7][i&127]=pwc[i]; }
  #pragma unroll
  for(int h=0;h<4;h++) patch1[t][h]=0.f;
  __syncthreads();
  int total0 = *cnt0; if(total0 > CAP) total0 = CAP;
  for(int i=t; i<total0; i+=256){
    int wv = wl0[i];
    int n = wv & 0xFFFF, hp = wv>>16;
    if((n>>8)==g){
      int nl = n & 255;
      float d[4]={0.f,0.f,0.f,0.f}, d2[4]={0.f,0.f,0.f,0.f};
      for(int l=0;l<32;l++){
        int j = hp*32+l;
        float base = new1c[(size_t)i*32+l] * s1s[j];
        #pragma unroll
        for(int h=0;h<4;h++){ d[h]+=base*w1s[h][j]; d2[h]+=base*wcs[h][j]; }
      }
      #pragma unroll
      for(int h=0;h<4;h++){
        atomicAdd(&patch1[nl][h], 0.25f*d[h]);
        atomicAdd(&pre2[n*4+h], 0.125f*d2[h]);
      }
    }
  }
  __syncthreads();
  const int n = g*256 + t;
  float4 p4 = ((const float4*)pre1)[n];
  float scv[4] = {p4.x+patch1[t][0], p4.y+patch1[t][1],
                  p4.z+patch1[t][2], p4.w+patch1[t][3]};
  float4 smout;
  unsigned kb = 0;
  #pragma unroll 1
  for(int h=0;h<4;h++){
    float m = blockMax4(scv[h], red);
    float e = expf(scv[h]-m);
    float ssum = blockSum4(e, red);
    float sm = e/(ssum + 1e-16f);
    float smax = blockMax4(sm, red);
    float thr = fminf(smax - 1e-7f, minscore);
    ((float*)&smout)[h] = sm;
    if(sm > thr){
      int p = atomicAdd(cnt1, 1);
      if(p < CAP){
        kb |= (1u<<h);
        wl1[p] = (h<<16) | n;
        idx1[n*4+h] = p;
      }
    }
  }
  __syncthreads();
  ((float4*)sm4out)[n] = smout;
  keep1[n] = (unsigned char)kb;
}

// ---------- layer-1 GraphConv(max): rows reconstructed from cur0 + new1c ----------
__global__ __launch_bounds__(256) void k_blockconv1(const float* __restrict__ cur0,
    const int* __restrict__ offs, const int* __restrict__ csr,
    const unsigned char* __restrict__ keep0, const int* __restrict__ idx0,
    const float* __restrict__ new1c,
    const unsigned char* __restrict__ keep1, const float* __restrict__ sm41,
    const int* __restrict__ cnt1, const int* __restrict__ wl1,
    const float* __restrict__ Wrel, const float* __restrict__ Wroot,
    const float* __restrict__ bias,
    float* __restrict__ new2c, float* __restrict__ bnsum, float* __restrict__ bnsq,
    const float* __restrict__ bns0, const float* __restrict__ bnq0,
    const float* __restrict__ g0, const float* __restrict__ b0bn,
    const float* __restrict__ bnsA, const float* __restrict__ bnqA,
    const float* __restrict__ g1v, const float* __restrict__ b1v){
  __shared__ __align__(16) float aggs[8][128];
  __shared__ __align__(16) float xps[8][128];
  __shared__ __align__(16) float sc0s[128], of0s[128], s1s[128], o1s[128];
  const int t = threadIdx.x, grp = t>>5, lane = t&31;
  if(t<128){
    float mu = bns0[t]*(1.0f/NN);
    float var = bnq0[t]*(1.0f/NN) - mu*mu;
    float sv = g0[t]*rsqrtf(var+1e-5f);
    sc0s[t]=sv; of0s[t]=b0bn[t]-mu*sv;
    float mu1 = bnsA[t]*(1.0f/NN);
    float var1 = bnqA[t]*(1.0f/NN) - mu1*mu1;
    float s1 = g1v[t]*rsqrtf(var1+1e-5f);
    s1s[t]=s1; o1s[t]=b1v[t]-mu1*s1;
  }
  __syncthreads();
  const float4 s0l = *(const float4*)&sc0s[lane*4];
  const float4 o0l = *(const float4*)&of0s[lane*4];
  const float4 s1l = *(const float4*)&s1s[lane*4];
  const float4 o1l = *(const float4*)&o1s[lane*4];
  const int hb = lane>>3;          // head-block of this lane's float4
  int total = *cnt1; if(total > CAP) total = CAP;
  for(int item = blockIdx.x*8 + grp; item < total; item += gridDim.x*8){
    const int wv = wl1[item];
    const int h = wv>>16, n = wv & 0xFFFF;
    const float smn = sm41[n*4+h];
    const int e0 = offs[n], e1 = offs[n+1];
    float4 acc = make_float4(-INFINITY,-INFINITY,-INFINITY,-INFINITY);
    bool any = false;
    for(int e=e0;e<e1;e++){
      int s = csr[e];
      if((keep1[s]>>h)&1){
        any = true;
        float sv = sm41[s*4+h];
        float4 c0 = ((const float4*)cur0)[s*32 + lane];
        float4 v;
        v.x = 0.5f*(s0l.x*c0.x+o0l.x) + 0.25f*o1l.x;
        v.y = 0.5f*(s0l.y*c0.y+o0l.y) + 0.25f*o1l.y;
        v.z = 0.5f*(s0l.z*c0.z+o0l.z) + 0.25f*o1l.z;
        v.w = 0.5f*(s0l.w*c0.w+o0l.w) + 0.25f*o1l.w;
        if((keep0[s]>>hb)&1){
          float4 nv = ((const float4*)(new1c + (size_t)idx0[s*4+hb]*32))[lane&7];
          v.x += 0.25f*s1l.x*nv.x; v.y += 0.25f*s1l.y*nv.y;
          v.z += 0.25f*s1l.z*nv.z; v.w += 0.25f*s1l.w*nv.w;
        }
        v.x*=sv; v.y*=sv; v.z*=sv; v.w*=sv;
        acc.x = fmaxf(acc.x, v.x); acc.y = fmaxf(acc.y, v.y);
        acc.z = fmaxf(acc.z, v.z); acc.w = fmaxf(acc.w, v.w);
      }
    }
    if(!any) acc = make_float4(0.f,0.f,0.f,0.f);
    *(float4*)&aggs[grp][lane*4] = acc;
    {
      float4 c0 = ((const float4*)cur0)[n*32 + lane];
      float4 v;
      v.x = 0.5f*(s0l.x*c0.x+o0l.x) + 0.25f*o1l.x;
      v.y = 0.5f*(s0l.y*c0.y+o0l.y) + 0.25f*o1l.y;
      v.z = 0.5f*(s0l.z*c0.z+o0l.z) + 0.25f*o1l.z;
      v.w = 0.5f*(s0l.w*c0.w+o0l.w) + 0.25f*o1l.w;
      if((keep0[n]>>hb)&1){
        float4 nv = ((const float4*)(new1c + (size_t)idx0[n*4+hb]*32))[lane&7];
        v.x += 0.25f*s1l.x*nv.x; v.y += 0.25f*s1l.y*nv.y;
        v.z += 0.25f*s1l.z*nv.z; v.w += 0.25f*s1l.w*nv.w;
      }
      v.x*=smn; v.y*=smn; v.z*=smn; v.w*=smn;
      *(float4*)&xps[grp][lane*4] = v;
    }
    const float* Wr = Wrel  + (size_t)(h*32+lane)*128;
    const float* Wo = Wroot + (size_t)(h*32+lane)*128;
    float o = bias[h*32+lane];
    for(int k=0;k<32;k++){
      float4 a  = *(const float4*)&aggs[grp][k*4];
      float4 xx = *(const float4*)&xps[grp][k*4];
      float4 wr = ((const float4*)Wr)[k];
      float4 wo = ((const float4*)Wo)[k];
      o += a.x*wr.x + a.y*wr.y + a.z*wr.z + a.w*wr.w;
      o += xx.x*wo.x + xx.y*wo.y + xx.z*wo.z + xx.w*wo.w;
    }
    o = lrelu(o);
    new2c[(size_t)item*32 + lane] = o;
    atomicAdd(&bnsum[h*32+lane], o);
    atomicAdd(&bnsq[h*32+lane], o*o);
  }
}

// ---------- cls: block per (graph,class); patch pre2 with layer-2 corr locally,
// select, reconstruct cur2 rows, attention + MLP ----------
__global__ __launch_bounds__(256) void k_cls2(const float* __restrict__ cur0,
    const unsigned char* __restrict__ keep0, const int* __restrict__ idx0,
    const float* __restrict__ new1c,
    const unsigned char* __restrict__ keep1, const int* __restrict__ idx1,
    const float* __restrict__ new2c,
    const float* __restrict__ pre2, const int* __restrict__ cnt1,
    const int* __restrict__ wl1, const float* __restrict__ pwc,
    const float* __restrict__ bns0, const float* __restrict__ bnq0,
    const float* __restrict__ g0, const float* __restrict__ b0bn,
    const float* __restrict__ bnsA, const float* __restrict__ bnqA,
    const float* __restrict__ g1v, const float* __restrict__ b1v,
    const float* __restrict__ bnsB, const float* __restrict__ bnqB,
    const float* __restrict__ g2v, const float* __restrict__ b2v,
    const float* __restrict__ gW1, const float* __restrict__ gb1,
    const float* __restrict__ gW2, const float* __restrict__ gb2,
    const float* __restrict__ fW1, const float* __restrict__ fb1,
    const float* __restrict__ fW2, const float* __restrict__ fb2,
    float* __restrict__ yws){
  __shared__ float red[4];
  __shared__ float sc0s[128], of0s[128], s1s[128], o1s[128], s2s[128], o2s[128];
  __shared__ float wc[128];
  __shared__ float patch[256];
  __shared__ int keptL[256];
  __shared__ float keptS[256];
  __shared__ float gateL[256];
  __shared__ __align__(16) float xk[128];
  __shared__ __align__(16) float pooled[128];
  __shared__ int nkept;
  const int t = threadIdx.x;
  const int g = blockIdx.x >> 2, c = blockIdx.x & 3;
  if(t<128){
    float mu = bns0[t]*(1.0f/NN);
    float var = bnq0[t]*(1.0f/NN) - mu*mu;
    float sv = g0[t]*rsqrtf(var+1e-5f);
    sc0s[t]=sv; of0s[t]=b0bn[t]-mu*sv;
    float mu1 = bnsA[t]*(1.0f/NN);
    float var1 = bnqA[t]*(1.0f/NN) - mu1*mu1;
    float s1 = g1v[t]*rsqrtf(var1+1e-5f);
    s1s[t]=s1; o1s[t]=b1v[t]-mu1*s1;
    float mu2 = bnsB[t]*(1.0f/NN);
    float var2 = bnqB[t]*(1.0f/NN) - mu2*mu2;
    float s2 = g2v[t]*rsqrtf(var2+1e-5f);
    s2s[t]=s2; o2s[t]=b2v[t]-mu2*s2;
    wc[t] = pwc[c*128+t];
  }
  patch[t]=0.f;
  __syncthreads();
  // patch: layer-2 corrections to cls scores for this graph
  int total1 = *cnt1; if(total1 > CAP) total1 = CAP;
  for(int i=t; i<total1; i+=256){
    int wv = wl1[i];
    int n = wv & 0xFFFF, hp = wv>>16;
    if((n>>8)==g){
      float d=0.f;
      for(int l=0;l<32;l++){
        int j = hp*32+l;
        d += new2c[(size_t)i*32+l]*s2s[j]*wc[j];
      }
      atomicAdd(&patch[n&255], 0.25f*d);
    }
  }
  __syncthreads();
  const int n = g*256 + t;
  float sc = pre2[n*4 + c] + patch[t];
  float m = blockMax4(sc, red);
  float e = expf(sc-m);
  float ssum = blockSum4(e, red);
  float sm = e/(ssum+1e-16f);
  float smax = blockMax4(sm, red);
  float thr = fminf(smax - 1e-7f, 0.8f);
  if(t==0) nkept = 0;
  __syncthreads();
  if(sm > thr){
    int p = atomicAdd(&nkept,1);
    keptL[p]=t; keptS[p]=sm;
  }
  __syncthreads();
  const int K = nkept;
  // gate per kept node
  for(int k=0;k<K;k++){
    int ln = keptL[k]; float sv = keptS[k];
    int nn = g*256 + ln;
    if(t<32){
      float4 c0 = ((const float4*)cur0)[nn*32 + t];
      float4 s0l = *(const float4*)&sc0s[t*4];
      float4 o0l = *(const float4*)&of0s[t*4];
      float4 s1l = *(const float4*)&s1s[t*4];
      float4 o1l = *(const float4*)&o1s[t*4];
      float4 s2l = *(const float4*)&s2s[t*4];
      float4 o2l = *(const float4*)&o2s[t*4];
      int hb = t>>3;
      float4 v1;
      v1.x = 0.5f*(s0l.x*c0.x+o0l.x) + 0.25f*o1l.x;
      v1.y = 0.5f*(s0l.y*c0.y+o0l.y) + 0.25f*o1l.y;
      v1.z = 0.5f*(s0l.z*c0.z+o0l.z) + 0.25f*o1l.z;
      v1.w = 0.5f*(s0l.w*c0.w+o0l.w) + 0.25f*o1l.w;
      if((keep0[nn]>>hb)&1){
        float4 nv = ((const float4*)(new1c + (size_t)idx0[nn*4+hb]*32))[t&7];
        v1.x += 0.25f*s1l.x*nv.x; v1.y += 0.25f*s1l.y*nv.y;
        v1.z += 0.25f*s1l.z*nv.z; v1.w += 0.25f*s1l.w*nv.w;
      }
      float4 v2;
      v2.x = 0.5f*v1.x + 0.25f*o2l.x;
      v2.y = 0.5f*v1.y + 0.25f*o2l.y;
      v2.z = 0.5f*v1.z + 0.25f*o2l.z;
      v2.w = 0.5f*v1.w + 0.25f*o2l.w;
      if((keep1[nn]>>hb)&1){
        float4 nv = ((const float4*)(new2c + (size_t)idx1[nn*4+hb]*32))[t&7];
        v2.x += 0.25f*s2l.x*nv.x; v2.y += 0.25f*s2l.y*nv.y;
        v2.z += 0.25f*s2l.z*nv.z; v2.w += 0.25f*s2l.w*nv.w;
      }
      v2.x*=sv; v2.y*=sv; v2.z*=sv; v2.w*=sv;
      *(float4*)&xk[t*4] = v2;
    }
    __syncthreads();
    float part = 0.f;
    if(t<128){
      const float* W = gW1 + (size_t)c*16384 + (size_t)t*128;
      float a = gb1[c*128+t];
      for(int f=0;f<32;f++){
        float4 xv = *(const float4*)&xk[f*4];
        float4 wv = ((const float4*)W)[f];
        a += xv.x*wv.x + xv.y*wv.y + xv.z*wv.z + xv.w*wv.w;
      }
      part = lrelu(a) * gW2[c*128+t];
    }
    float gs = blockSum4(part, red);
    if(t==0) gateL[k] = gs + gb2[c];
    __syncthreads();
  }
  float gv = (t<K)? gateL[t] : -INFINITY;
  float gm = blockMax4(gv, red);
  float ge = (t<K)? expf(gv-gm) : 0.f;
  float gsum = blockSum4(ge, red);
  if(t<K) gateL[t] = ge/(gsum+1e-16f);
  __syncthreads();
  if(t<128){
    int hb = t>>5, l = t&31;
    float acc = 0.f;
    for(int k=0;k<K;k++){
      int nn = g*256 + keptL[k];
      float c0 = cur0[(size_t)nn*128 + t];
      float v1 = 0.5f*(sc0s[t]*c0 + of0s[t]) + 0.25f*o1s[t];
      if((keep0[nn]>>hb)&1) v1 += 0.25f*s1s[t]*new1c[(size_t)idx0[nn*4+hb]*32 + l];
      float v2 = 0.5f*v1 + 0.25f*o2s[t];
      if((keep1[nn]>>hb)&1) v2 += 0.25f*s2s[t]*new2c[(size_t)idx1[nn*4+hb]*32 + l];
      acc += gateL[k]*keptS[k]*v2;
    }
    pooled[t]=acc;
  }
  __syncthreads();
  float part2=0.f;
  if(t<128){
    const float* F = fW1 + (size_t)c*16384 + (size_t)t*128;
    float a = fb1[c*128+t];
    for(int f=0;f<32;f++){
      float4 xv = *(const float4*)&pooled[f*4];
      float4 wv = ((const float4*)F)[f];
      a += xv.x*wv.x + xv.y*wv.y + xv.z*wv.z + xv.w*wv.w;
    }
    part2 = lrelu(a) * fW2[c*128+t];
  }
  float ysum = blockSum4(part2, red);
  if(t==0) yws[g*4+c] = ysum + fb2[c];
}

// ---------- final per-graph log_softmax over 4 class logits ----------
__global__ __launch_bounds__(256) void k_clsfin(const float* __restrict__ yws,
                                                float* __restrict__ out){
  const int g = threadIdx.x;
  float4 y = ((const float4*)yws)[g];
  float m = fmaxf(fmaxf(y.x,y.y), fmaxf(y.z,y.w));
  float l = logf(expf(y.x-m)+expf(y.y-m)+expf(y.z-m)+expf(y.w-m));
  ((float4*)out)[g] = make_float4(y.x-m-l, y.y-m-l, y.z-m-l, y.w-m-l);
}

extern "C" void kernel_launch(void* const* d_in, const int* in_sizes, int n_in,
                              void* d_out, int out_size, void* d_ws, size_t ws_size,
                              hipStream_t stream){
  (void)in_sizes; (void)n_in; (void)out_size; (void)ws_size;
  const float* x     = (const float*)d_in[0];
  const int*   ei    = (const int*)d_in[1];
  const float* Wrel0 = (const float*)d_in[3];
  const float* Wroot0= (const float*)d_in[4];
  const float* b0    = (const float*)d_in[5];
  const float* bn0g  = (const float*)d_in[6];
  const float* bn0b  = (const float*)d_in[7];
  const float* bpw   = (const float*)d_in[8];
  const float* bWrel = (const float*)d_in[9];
  const float* bWroot= (const float*)d_in[10];
  const float* bbv   = (const float*)d_in[11];
  const float* bbng  = (const float*)d_in[12];
  const float* bbnb  = (const float*)d_in[13];
  const float* cpw   = (const float*)d_in[14];
  const float* gW1   = (const float*)d_in[15];
  const float* gb1   = (const float*)d_in[16];
  const float* gW2   = (const float*)d_in[17];
  const float* gb2   = (const float*)d_in[18];
  const float* fW1   = (const float*)d_in[19];
  const float* fb1   = (const float*)d_in[20];
  const float* fW2   = (const float*)d_in[21];
  const float* fb2   = (const float*)d_in[22];

  char* ws = (char*)d_ws;
  float* cur0  = (float*)(ws + 0);                  // 33.55 MB
  float* new1c = (float*)(ws + 33554432ull);        // 16.78 MB (CAP*32 floats)
  float* new2c = (float*)(ws + 50331648ull);        // 16.78 MB (aliases agg0)
  float* agg0  = new2c;                             // dead before new2c written
  int*   csr   = (int*)(ws + 67108864ull);          // 2 MB
  float* scores0=(float*)(ws + 69206016ull);        // 1 MB (sm4_0 aliases)
  float* sm40  = scores0;
  float* pre1  = (float*)(ws + 70254592ull);        // 1 MB (sm4_1 aliases)
  float* sm41  = pre1;
  float* pre2  = (float*)(ws + 71303168ull);        // 1 MB
  int*   wl0   = (int*)(ws + 72351744ull);          // 512 KB
  int*   wl1   = (int*)(ws + 72876032ull);          // 512 KB
  int*   offs  = (int*)(ws + 73400320ull);          // 256 KB + 4
  int*   cursor= (int*)(ws + 73666560ull);          // 256 KB
  unsigned char* keep0 = (unsigned char*)(ws + 73928704ull); // 64 KB
  unsigned char* keep1 = (unsigned char*)(ws + 73994240ull); // 64 KB
  int*   idx0  = (int*)(ws + 74059776ull);          // 1 MB
  int*   idx1  = (int*)(ws + 75108352ull);          // 1 MB
  char*  Z     = ws + 76156928ull;                  // zero-init region
  int*   deg   = (int*)Z;                           // 256 KB
  float* bnsum0= (float*)(Z + 262144);
  float* bnsq0 = (float*)(Z + 262656);
  float* bnA   = (float*)(Z + 263168);
  float* bqA   = (float*)(Z + 263680);
  float* bnB   = (float*)(Z + 264192);
  float* bqB   = (float*)(Z + 264704);
  int*   cnt0  = (int*)(Z + 265216);
  int*   cnt1  = (int*)(Z + 265220);
  float* yws   = (float*)(Z + 266240);              // 4 KB

  hipMemsetAsync(Z, 0, 270336, stream);
  hipMemsetAsync(idx0, 0xFF, 2097152, stream);      // idx0+idx1 contiguous

  // CSR by dst
  k_count  <<<2048,256,0,stream>>>(ei, deg);
  k_scan   <<<1,1024,0,stream>>>(deg, offs, cursor);
  k_scatter<<<2048,256,0,stream>>>(ei, cursor, csr);

  // conv0 -> lrelu (+ fused bn0 stats; bn0 apply stays folded downstream)
  k_agg0    <<<4096,256,0,stream>>>(x, offs, csr, agg0);
  k_conv0mm <<<512,256,0,stream>>>(agg0, x, Wrel0, Wroot0, b0, cur0, bnsum0, bnsq0);

  // single pass: scores for pool0 + pre-scores for pool1/cls
  k_scores<<<8192,256,0,stream>>>(cur0, bnsum0, bnsq0, bn0g,
                                  bpw, bpw + 512, cpw, scores0, pre1, pre2);

  // pool layer 0 select
  k_poolsel<<<256,256,0,stream>>>(scores0, 0.7f, sm40, keep0, cnt0, wl0, idx0);

  // layer-0 conv on kept items
  k_blockconv0<<<256,256,0,stream>>>(cur0, offs, csr, keep0, sm40, cnt0, wl0,
                                     bWrel, bWroot, bbv, new1c, bnA, bqA,
                                     bnsum0, bnsq0, bn0g, bn0b);

  // pool layer 1 select (patches pre1 with layer-1 corr, pre2 partially)
  k_poolsel1<<<256,256,0,stream>>>(pre1, pre2, cnt0, wl0, new1c,
                                   bnA, bqA, bbng,
                                   bpw + 512, cpw,
                                   0.7f, sm41, keep1, cnt1, wl1, idx1);

  // layer-1 conv on kept items (rows reconstructed)
  k_blockconv1<<<256,256,0,stream>>>(cur0, offs, csr, keep0, idx0, new1c,
                                     keep1, sm41, cnt1, wl1,
                                     bWrel + 16384, bWroot + 16384, bbv + 128,
                                     new2c, bnB, bqB,
                                     bnsum0, bnsq0, bn0g, bn0b,
                                     bnA, bqA, bbng, bbnb);

  // classification heads (patch pre2 with layer-2 corr in-block)
  k_cls2<<<1024,256,0,stream>>>(cur0, keep0, idx0, new1c, keep1, idx1, new2c,
                                pre2, cnt1, wl1, cpw,
                                bnsum0, bnsq0, bn0g, bn0b,
                                bnA, bqA, bbng, bbnb,
                                bnB, bqB, bbng + 128, bbnb + 128,
                                gW1, gb1, gW2, gb2, fW1, fb1, fW2, fb2, yws);
  k_clsfin<<<1,256,0,stream>>>(yws, (float*)d_out);
}

// Round 9
// 384.057 us; speedup vs baseline: 1.2589x; 1.0037x over previous
//
#include <hip/hip_runtime.h>
#include <math.h>

#define NN 65536      // nodes
#define NE 524288     // edges
#define NG 256        // graphs (256 contiguous nodes each)
#define SLOPE 0.01f
#define CAP 131072    // worklist capacity per layer (typ. ~1k items)

__device__ __forceinline__ float lrelu(float v){ return v > 0.f ? v : SLOPE*v; }

// ---------- block reductions (256-thread blocks = 4 waves) ----------
__device__ __forceinline__ float blockMax4(float v, float* s4){
  #pragma unroll
  for(int o=32;o>0;o>>=1) v = fmaxf(v, __shfl_down(v, o, 64));
  int t = threadIdx.x;
  __syncthreads();
  if((t&63)==0) s4[t>>6] = v;
  __syncthreads();
  return fmaxf(fmaxf(s4[0], s4[1]), fmaxf(s4[2], s4[3]));
}
__device__ __forceinline__ float blockSum4(float v, float* s4){
  #pragma unroll
  for(int o=32;o>0;o>>=1) v += __shfl_down(v, o, 64);
  int t = threadIdx.x;
  __syncthreads();
  if((t&63)==0) s4[t>>6] = v;
  __syncthreads();
  return (s4[0]+s4[1])+(s4[2]+s4[3]);
}

// ---------- CSR build (by dst) ----------
__global__ __launch_bounds__(256) void k_count(const int* __restrict__ ei, int* __restrict__ deg){
  int e = blockIdx.x*256 + threadIdx.x;
  if(e < NE) atomicAdd(&deg[ei[NE + e]], 1);
}

__global__ __launch_bounds__(1024) void k_scan(const int* __restrict__ deg,
      int* __restrict__ offs, int* __restrict__ cursor){
  __shared__ int part[1024];
  int t = threadIdx.x;
  const int4* d4 = (const int4*)(deg + t*64);
  int4 buf[16];
  int s=0;
  #pragma unroll
  for(int i=0;i<16;i++){ buf[i]=d4[i]; s += buf[i].x+buf[i].y+buf[i].z+buf[i].w; }
  part[t]=s;
  __syncthreads();
  for(int off=1; off<1024; off<<=1){
    int v = (t>=off)? part[t-off] : 0;
    __syncthreads();
    part[t] += v;
    __syncthreads();
  }
  int run = (t==0)? 0 : part[t-1];
  #pragma unroll
  for(int i=0;i<16;i++){
    int4 d = buf[i];
    int4 o;
    o.x = run; run += d.x;
    o.y = run; run += d.y;
    o.z = run; run += d.z;
    o.w = run; run += d.w;
    ((int4*)(offs + t*64))[i] = o;
    ((int4*)(cursor + t*64))[i] = o;
  }
  if(t==1023) offs[NN] = run;
}

__global__ __launch_bounds__(256) void k_scatter(const int* __restrict__ ei,
      int* __restrict__ cursor, int* __restrict__ csr){
  int e = blockIdx.x*256 + threadIdx.x;
  if(e < NE){
    int d = ei[NE + e];
    int p = atomicAdd(&cursor[d], 1);
    csr[p] = ei[e];
  }
}

// ---------- conv0: agg[i] = max over in-edges of x[src], else 0 ----------
__global__ __launch_bounds__(256) void k_agg0(const float* __restrict__ x,
    const int* __restrict__ offs, const int* __restrict__ csr, float* __restrict__ agg0){
  int tid = blockIdx.x*256 + threadIdx.x;
  int node = tid>>4, q = tid&15;
  int e0 = offs[node], e1 = offs[node+1];
  float4 acc = make_float4(0.f,0.f,0.f,0.f);
  if(e0 < e1){
    acc = make_float4(-INFINITY,-INFINITY,-INFINITY,-INFINITY);
    int e = e0;
    for(; e+7 < e1; e += 8){
      int si[8];
      #pragma unroll
      for(int u=0;u<8;u++) si[u] = csr[e+u];
      float4 v[8];
      #pragma unroll
      for(int u=0;u<8;u++) v[u] = ((const float4*)x)[si[u]*16 + q];
      #pragma unroll
      for(int u=0;u<8;u++){
        acc.x=fmaxf(acc.x,v[u].x); acc.y=fmaxf(acc.y,v[u].y);
        acc.z=fmaxf(acc.z,v[u].z); acc.w=fmaxf(acc.w,v[u].w);
      }
    }
    for(; e < e1; e++){
      int s0 = csr[e];
      float4 v0 = ((const float4*)x)[s0*16 + q];
      acc.x=fmaxf(acc.x,v0.x); acc.y=fmaxf(acc.y,v0.y);
      acc.z=fmaxf(acc.z,v0.z); acc.w=fmaxf(acc.w,v0.w);
    }
  }
  ((float4*)agg0)[node*16 + q] = acc;
}

// ---------- conv0 matmul: cur0 = lrelu([agg0|x] @ [Wrel|Wroot]^T + b0) ----------
// 128x128 tile, 8x8 microtile, XOR-swizzled LDS. Spill fix (r9): k4 loop kept
// at unroll 1 and W fragments STREAMED one float4 at a time (peak live ~120
// regs: 64 acc + 32 a4 + 4 w4) — r5/r8's batch a4[8]+w4[8] + unroll-4 hoisting
// made the scheduler keep ~64 ds_read results live -> RA spilled (88 VGPR,
// +16MB scratch writes).
__global__ __launch_bounds__(256, 2) void k_conv0mm(
    const float* __restrict__ agg0, const float* __restrict__ x,
    const float* __restrict__ Wrel, const float* __restrict__ Wroot,
    const float* __restrict__ b0, float* __restrict__ cur,
    float* __restrict__ bnsum, float* __restrict__ bnsq){
  __shared__ float4 As[2048];
  __shared__ float4 Ws[2048];
  const int t = threadIdx.x;
  const int tn = t & 15;
  const int tc = t >> 4;
  float acc[8][8];
  #pragma unroll
  for(int i=0;i<8;i++)
    #pragma unroll
    for(int j=0;j<8;j++) acc[i][j]=0.f;

  const size_t tileoff = (size_t)blockIdx.x * 8192;
  #pragma unroll 1
  for(int ch=0; ch<2; ch++){
    const float4* gA = (const float4*)((ch==0? agg0 : x) + tileoff);
    const float4* gW = (const float4*)(ch==0? Wrel : Wroot);
    __syncthreads();
    #pragma unroll
    for(int i=0;i<8;i++){
      int idx = t + i*256;
      int n = idx>>4, k4 = idx&15;
      int sw = n*16 + ((k4 + (n>>3))&15);
      As[sw] = gA[idx];
      Ws[sw] = gW[idx];
    }
    __syncthreads();
    #pragma unroll 1
    for(int k4=0;k4<16;k4++){
      float4 a4[8];
      #pragma unroll
      for(int i=0;i<8;i++) a4[i] = As[(tn*8+i)*16 + ((k4+tn)&15)];
      #pragma unroll
      for(int j=0;j<8;j++){
        float4 w4 = Ws[(tc*8+j)*16 + ((k4+tc)&15)];
        #pragma unroll
        for(int i=0;i<8;i++){
          acc[i][j] = fmaf(a4[i].x, w4.x, acc[i][j]);
          acc[i][j] = fmaf(a4[i].y, w4.y, acc[i][j]);
          acc[i][j] = fmaf(a4[i].z, w4.z, acc[i][j]);
          acc[i][j] = fmaf(a4[i].w, w4.w, acc[i][j]);
        }
      }
    }
  }

  float bj[8];
  #pragma unroll
  for(int j=0;j<8;j++) bj[j] = b0[tc*8+j];
  float cs[8], cq[8];
  #pragma unroll
  for(int j=0;j<8;j++){ cs[j]=0.f; cq[j]=0.f; }
  const int nbase = blockIdx.x*128;
  #pragma unroll
  for(int i=0;i<8;i++){
    int node = nbase + tn*8 + i;
    float v[8];
    #pragma unroll
    for(int j=0;j<8;j++){
      v[j] = lrelu(acc[i][j] + bj[j]);
      cs[j] += v[j]; cq[j] += v[j]*v[j];
    }
    float4 o0 = make_float4(v[0],v[1],v[2],v[3]);
    float4 o1 = make_float4(v[4],v[5],v[6],v[7]);
    ((float4*)cur)[node*32 + tc*2 + 0] = o0;
    ((float4*)cur)[node*32 + tc*2 + 1] = o1;
  }
  __syncthreads();
  float* reds = (float*)As;
  float* redq = (float*)Ws;
  #pragma unroll
  for(int j=0;j<8;j++){
    reds[(tc*8+j)*16 + tn] = cs[j];
    redq[(tc*8+j)*16 + tn] = cq[j];
  }
  __syncthreads();
  if(t<128){
    float S=0.f, Q=0.f;
    #pragma unroll
    for(int i=0;i<16;i++){ S += reds[t*16+i]; Q += redq[t*16+i]; }
    atomicAdd(&bnsum[t], S);
    atomicAdd(&bnsq[t], Q);
  }
}

// ---------- one pass over cur0: scores for pool0, pool1, cls (affine fold) ----------
__global__ __launch_bounds__(256) void k_scores(const float* __restrict__ cur0,
    const float* __restrict__ bns0, const float* __restrict__ bnq0,
    const float* __restrict__ g0,
    const float* __restrict__ pw0, const float* __restrict__ pw1,
    const float* __restrict__ pwc,
    float* __restrict__ scores0, float* __restrict__ pre1, float* __restrict__ pre2){
  __shared__ __align__(16) float w[12][128];
  __shared__ float sc0s[128];
  const int t = threadIdx.x;
  if(t<128){
    float mu = bns0[t]*(1.0f/NN);
    float var = bnq0[t]*(1.0f/NN) - mu*mu;
    sc0s[t] = g0[t]*rsqrtf(var+1e-5f);
  }
  __syncthreads();
  for(int i=t;i<512;i+=256){
    int h=i>>7, j=i&127;
    float s = sc0s[j];
    w[h][j]   = pw0[i]*s;
    w[4+h][j] = pw1[i]*(0.5f*s);
    w[8+h][j] = pwc[i]*(0.25f*s);
  }
  __syncthreads();
  const int tid = blockIdx.x*256 + t;
  const int n = tid>>5, k = tid&31;
  float4 v = ((const float4*)cur0)[tid];
  float a[12];
  #pragma unroll
  for(int q=0;q<12;q++){
    float4 wv = *(const float4*)&w[q][k*4];
    a[q] = v.x*wv.x + v.y*wv.y + v.z*wv.z + v.w*wv.w;
  }
  #pragma unroll
  for(int o=16;o>0;o>>=1){
    #pragma unroll
    for(int q=0;q<12;q++) a[q] += __shfl_down(a[q], o, 32);
  }
  if(k==0){
    ((float4*)scores0)[n] = make_float4(a[0],a[1],a[2],a[3]);
    ((float4*)pre1)[n]    = make_float4(a[4],a[5],a[6],a[7]);
    ((float4*)pre2)[n]    = make_float4(a[8],a[9],a[10],a[11]);
  }
}

// ---------- pool select layer 0 (sm4 aliases scores: read-before-write) ----------
__global__ __launch_bounds__(256) void k_poolsel(const float* __restrict__ scores,
    float minscore, float* __restrict__ sm4, unsigned char* __restrict__ keep,
    int* __restrict__ cnt, int* __restrict__ wl, int* __restrict__ idx){
  __shared__ float red[4];
  const int t = threadIdx.x, g = blockIdx.x, n = g*256 + t;
  float4 s4 = ((const float4*)scores)[n];
  float scv[4] = {s4.x, s4.y, s4.z, s4.w};
  float4 smout;
  unsigned kb = 0;
  #pragma unroll 1
  for(int h=0;h<4;h++){
    float m = blockMax4(scv[h], red);
    float e = expf(scv[h]-m);
    float ssum = blockSum4(e, red);
    float sm = e/(ssum + 1e-16f);
    float smax = blockMax4(sm, red);
    float thr = fminf(smax - 1e-7f, minscore);
    ((float*)&smout)[h] = sm;
    if(sm > thr){
      int p = atomicAdd(cnt, 1);
      if(p < CAP){
        kb |= (1u<<h);
        wl[p] = (h<<16) | n;
        idx[n*4+h] = p;
      }
    }
  }
  __syncthreads();
  ((float4*)sm4)[n] = smout;
  keep[n] = (unsigned char)kb;
}

// ---------- layer-0 GraphConv(max) on kept items (rows = bn0(cur0)) ----------
__global__ __launch_bounds__(256) void k_blockconv0(const float* __restrict__ cur0,
    const int* __restrict__ offs, const int* __restrict__ csr,
    const unsigned char* __restrict__ keep, const float* __restrict__ sm4,
    const int* __restrict__ cnt, const int* __restrict__ wl,
    const float* __restrict__ Wrel, const float* __restrict__ Wroot,
    const float* __restrict__ bias,
    float* __restrict__ new1c, float* __restrict__ bnsum, float* __restrict__ bnsq,
    const float* __restrict__ bns0, const float* __restrict__ bnq0,
    const float* __restrict__ g0, const float* __restrict__ b0bn){
  __shared__ __align__(16) float aggs[8][128];
  __shared__ __align__(16) float xps[8][128];
  __shared__ __align__(16) float scv[128];
  __shared__ __align__(16) float ofv[128];
  const int t = threadIdx.x, grp = t>>5, lane = t&31;
  if(t<128){
    float mu = bns0[t]*(1.0f/NN);
    float var = bnq0[t]*(1.0f/NN) - mu*mu;
    float sv = g0[t]*rsqrtf(var+1e-5f);
    scv[t]=sv; ofv[t]=b0bn[t]-mu*sv;
  }
  __syncthreads();
  const float4 s4l = *(const float4*)&scv[lane*4];
  const float4 o4l = *(const float4*)&ofv[lane*4];
  int total = *cnt; if(total > CAP) total = CAP;
  for(int item = blockIdx.x*8 + grp; item < total; item += gridDim.x*8){
    const int wv = wl[item];
    const int h = wv>>16, n = wv & 0xFFFF;
    const float smn = sm4[n*4+h];
    const int e0 = offs[n], e1 = offs[n+1];
    float4 acc = make_float4(-INFINITY,-INFINITY,-INFINITY,-INFINITY);
    bool any = false;
    for(int e=e0;e<e1;e++){
      int s = csr[e];
      if((keep[s]>>h)&1){
        any = true;
        float sv = sm4[s*4+h];
        float4 v = ((const float4*)cur0)[s*32 + lane];
        v.x = (v.x*s4l.x + o4l.x)*sv; v.y = (v.y*s4l.y + o4l.y)*sv;
        v.z = (v.z*s4l.z + o4l.z)*sv; v.w = (v.w*s4l.w + o4l.w)*sv;
        acc.x = fmaxf(acc.x, v.x); acc.y = fmaxf(acc.y, v.y);
        acc.z = fmaxf(acc.z, v.z); acc.w = fmaxf(acc.w, v.w);
      }
    }
    if(!any) acc = make_float4(0.f,0.f,0.f,0.f);
    *(float4*)&aggs[grp][lane*4] = acc;
    float4 xv = ((const float4*)cur0)[n*32 + lane];
    xv.x = (xv.x*s4l.x + o4l.x)*smn; xv.y = (xv.y*s4l.y + o4l.y)*smn;
    xv.z = (xv.z*s4l.z + o4l.z)*smn; xv.w = (xv.w*s4l.w + o4l.w)*smn;
    *(float4*)&xps[grp][lane*4] = xv;
    // half-wave group: LDS write->read program-ordered within the wave
    const float* Wr = Wrel  + (size_t)(h*32+lane)*128;
    const float* Wo = Wroot + (size_t)(h*32+lane)*128;
    float o = bias[h*32+lane];
    for(int k=0;k<32;k++){
      float4 a  = *(const float4*)&aggs[grp][k*4];
      float4 xx = *(const float4*)&xps[grp][k*4];
      float4 wr = ((const float4*)Wr)[k];
      float4 wo = ((const float4*)Wo)[k];
      o += a.x*wr.x + a.y*wr.y + a.z*wr.z + a.w*wr.w;
      o += xx.x*wo.x + xx.y*wo.y + xx.z*wo.z + xx.w*wo.w;
    }
    o = lrelu(o);
    new1c[(size_t)item*32 + lane] = o;
    atomicAdd(&bnsum[h*32+lane], o);
    atomicAdd(&bnsq[h*32+lane], o*o);
  }
}

// ---------- pool select layer 1: patch pre1 (and pre2) with layer-1 corrections,
// then softmax/keep. sm4out aliases pre1 (read-before-write). ----------
__global__ __launch_bounds__(256) void k_poolsel1(
    const float* __restrict__ pre1, float* __restrict__ pre2,
    const int* __restrict__ cnt0, const int* __restrict__ wl0,
    const float* __restrict__ new1c,
    const float* __restrict__ bnsA, const float* __restrict__ bnqA,
    const float* __restrict__ g1v,
    const float* __restrict__ pw1, const float* __restrict__ pwc,
    float minscore, float* __restrict__ sm4out, unsigned char* __restrict__ keep1,
    int* __restrict__ cnt1, int* __restrict__ wl1, int* __restrict__ idx1){
  __shared__ float red[4];
  __shared__ float s1s[128];
  __shared__ __align__(16) float w1s[4][128];
  __shared__ __align__(16) float wcs[4][128];
  __shared__ float patch1[256][4];
  const int t = threadIdx.x, g = blockIdx.x;
  if(t<128){
    float mu = bnsA[t]*(1.0f/NN);
    float var = bnqA[t]*(1.0f/NN) - mu*mu;
    s1s[t] = g1v[t]*rsqrtf(var+1e-5f);
  }
  for(int i=t;i<512;i+=256){ w1s[i>>7][i&127]=pw1[i]; wcs[i>>7][i&127]=pwc[i]; }
  #pragma unroll
  for(int h=0;h<4;h++) patch1[t][h]=0.f;
  __syncthreads();
  int total0 = *cnt0; if(total0 > CAP) total0 = CAP;
  for(int i=t; i<total0; i+=256){
    int wv = wl0[i];
    int n = wv & 0xFFFF, hp = wv>>16;
    if((n>>8)==g){
      int nl = n & 255;
      float d[4]={0.f,0.f,0.f,0.f}, d2[4]={0.f,0.f,0.f,0.f};
      for(int l=0;l<32;l++){
        int j = hp*32+l;
        float base = new1c[(size_t)i*32+l] * s1s[j];
        #pragma unroll
        for(int h=0;h<4;h++){ d[h]+=base*w1s[h][j]; d2[h]+=base*wcs[h][j]; }
      }
      #pragma unroll
      for(int h=0;h<4;h++){
        atomicAdd(&patch1[nl][h], 0.25f*d[h]);
        atomicAdd(&pre2[n*4+h], 0.125f*d2[h]);
      }
    }
  }
  __syncthreads();
  const int n = g*256 + t;
  float4 p4 = ((const float4*)pre1)[n];
  float scv[4] = {p4.x+patch1[t][0], p4.y+patch1[t][1],
                  p4.z+patch1[t][2], p4.w+patch1[t][3]};
  float4 smout;
  unsigned kb = 0;
  #pragma unroll 1
  for(int h=0;h<4;h++){
    float m = blockMax4(scv[h], red);
    float e = expf(scv[h]-m);
    float ssum = blockSum4(e, red);
    float sm = e/(ssum + 1e-16f);
    float smax = blockMax4(sm, red);
    float thr = fminf(smax - 1e-7f, minscore);
    ((float*)&smout)[h] = sm;
    if(sm > thr){
      int p = atomicAdd(cnt1, 1);
      if(p < CAP){
        kb |= (1u<<h);
        wl1[p] = (h<<16) | n;
        idx1[n*4+h] = p;
      }
    }
  }
  __syncthreads();
  ((float4*)sm4out)[n] = smout;
  keep1[n] = (unsigned char)kb;
}

// ---------- layer-1 GraphConv(max): rows reconstructed from cur0 + new1c ----------
__global__ __launch_bounds__(256) void k_blockconv1(const float* __restrict__ cur0,
    const int* __restrict__ offs, const int* __restrict__ csr,
    const unsigned char* __restrict__ keep0, const int* __restrict__ idx0,
    const float* __restrict__ new1c,
    const unsigned char* __restrict__ keep1, const float* __restrict__ sm41,
    const int* __restrict__ cnt1, const int* __restrict__ wl1,
    const float* __restrict__ Wrel, const float* __restrict__ Wroot,
    const float* __restrict__ bias,
    float* __restrict__ new2c, float* __restrict__ bnsum, float* __restrict__ bnsq,
    const float* __restrict__ bns0, const float* __restrict__ bnq0,
    const float* __restrict__ g0, const float* __restrict__ b0bn,
    const float* __restrict__ bnsA, const float* __restrict__ bnqA,
    const float* __restrict__ g1v, const float* __restrict__ b1v){
  __shared__ __align__(16) float aggs[8][128];
  __shared__ __align__(16) float xps[8][128];
  __shared__ __align__(16) float sc0s[128], of0s[128], s1s[128], o1s[128];
  const int t = threadIdx.x, grp = t>>5, lane = t&31;
  if(t<128){
    float mu = bns0[t]*(1.0f/NN);
    float var = bnq0[t]*(1.0f/NN) - mu*mu;
    float sv = g0[t]*rsqrtf(var+1e-5f);
    sc0s[t]=sv; of0s[t]=b0bn[t]-mu*sv;
    float mu1 = bnsA[t]*(1.0f/NN);
    float var1 = bnqA[t]*(1.0f/NN) - mu1*mu1;
    float s1 = g1v[t]*rsqrtf(var1+1e-5f);
    s1s[t]=s1; o1s[t]=b1v[t]-mu1*s1;
  }
  __syncthreads();
  const float4 s0l = *(const float4*)&sc0s[lane*4];
  const float4 o0l = *(const float4*)&of0s[lane*4];
  const float4 s1l = *(const float4*)&s1s[lane*4];
  const float4 o1l = *(const float4*)&o1s[lane*4];
  const int hb = lane>>3;
  int total = *cnt1; if(total > CAP) total = CAP;
  for(int item = blockIdx.x*8 + grp; item < total; item += gridDim.x*8){
    const int wv = wl1[item];
    const int h = wv>>16, n = wv & 0xFFFF;
    const float smn = sm41[n*4+h];
    const int e0 = offs[n], e1 = offs[n+1];
    float4 acc = make_float4(-INFINITY,-INFINITY,-INFINITY,-INFINITY);
    bool any = false;
    for(int e=e0;e<e1;e++){
      int s = csr[e];
      if((keep1[s]>>h)&1){
        any = true;
        float sv = sm41[s*4+h];
        float4 c0 = ((const float4*)cur0)[s*32 + lane];
        float4 v;
        v.x = 0.5f*(s0l.x*c0.x+o0l.x) + 0.25f*o1l.x;
        v.y = 0.5f*(s0l.y*c0.y+o0l.y) + 0.25f*o1l.y;
        v.z = 0.5f*(s0l.z*c0.z+o0l.z) + 0.25f*o1l.z;
        v.w = 0.5f*(s0l.w*c0.w+o0l.w) + 0.25f*o1l.w;
        if((keep0[s]>>hb)&1){
          float4 nv = ((const float4*)(new1c + (size_t)idx0[s*4+hb]*32))[lane&7];
          v.x += 0.25f*s1l.x*nv.x; v.y += 0.25f*s1l.y*nv.y;
          v.z += 0.25f*s1l.z*nv.z; v.w += 0.25f*s1l.w*nv.w;
        }
        v.x*=sv; v.y*=sv; v.z*=sv; v.w*=sv;
        acc.x = fmaxf(acc.x, v.x); acc.y = fmaxf(acc.y, v.y);
        acc.z = fmaxf(acc.z, v.z); acc.w = fmaxf(acc.w, v.w);
      }
    }
    if(!any) acc = make_float4(0.f,0.f,0.f,0.f);
    *(float4*)&aggs[grp][lane*4] = acc;
    {
      float4 c0 = ((const float4*)cur0)[n*32 + lane];
      float4 v;
      v.x = 0.5f*(s0l.x*c0.x+o0l.x) + 0.25f*o1l.x;
      v.y = 0.5f*(s0l.y*c0.y+o0l.y) + 0.25f*o1l.y;
      v.z = 0.5f*(s0l.z*c0.z+o0l.z) + 0.25f*o1l.z;
      v.w = 0.5f*(s0l.w*c0.w+o0l.w) + 0.25f*o1l.w;
      if((keep0[n]>>hb)&1){
        float4 nv = ((const float4*)(new1c + (size_t)idx0[n*4+hb]*32))[lane&7];
        v.x += 0.25f*s1l.x*nv.x; v.y += 0.25f*s1l.y*nv.y;
        v.z += 0.25f*s1l.z*nv.z; v.w += 0.25f*s1l.w*nv.w;
      }
      v.x*=smn; v.y*=smn; v.z*=smn; v.w*=smn;
      *(float4*)&xps[grp][lane*4] = v;
    }
    const float* Wr = Wrel  + (size_t)(h*32+lane)*128;
    const float* Wo = Wroot + (size_t)(h*32+lane)*128;
    float o = bias[h*32+lane];
    for(int k=0;k<32;k++){
      float4 a  = *(const float4*)&aggs[grp][k*4];
      float4 xx = *(const float4*)&xps[grp][k*4];
      float4 wr = ((const float4*)Wr)[k];
      float4 wo = ((const float4*)Wo)[k];
      o += a.x*wr.x + a.y*wr.y + a.z*wr.z + a.w*wr.w;
      o += xx.x*wo.x + xx.y*wo.y + xx.z*wo.z + xx.w*wo.w;
    }
    o = lrelu(o);
    new2c[(size_t)item*32 + lane] = o;
    atomicAdd(&bnsum[h*32+lane], o);
    atomicAdd(&bnsq[h*32+lane], o*o);
  }
}

// ---------- cls: block per (graph,class) ----------
__global__ __launch_bounds__(256) void k_cls2(const float* __restrict__ cur0,
    const unsigned char* __restrict__ keep0, const int* __restrict__ idx0,
    const float* __restrict__ new1c,
    const unsigned char* __restrict__ keep1, const int* __restrict__ idx1,
    const float* __restrict__ new2c,
    const float* __restrict__ pre2, const int* __restrict__ cnt1,
    const int* __restrict__ wl1, const float* __restrict__ pwc,
    const float* __restrict__ bns0, const float* __restrict__ bnq0,
    const float* __restrict__ g0, const float* __restrict__ b0bn,
    const float* __restrict__ bnsA, const float* __restrict__ bnqA,
    const float* __restrict__ g1v, const float* __restrict__ b1v,
    const float* __restrict__ bnsB, const float* __restrict__ bnqB,
    const float* __restrict__ g2v, const float* __restrict__ b2v,
    const float* __restrict__ gW1, const float* __restrict__ gb1,
    const float* __restrict__ gW2, const float* __restrict__ gb2,
    const float* __restrict__ fW1, const float* __restrict__ fb1,
    const float* __restrict__ fW2, const float* __restrict__ fb2,
    float* __restrict__ yws){
  __shared__ float red[4];
  __shared__ float sc0s[128], of0s[128], s1s[128], o1s[128], s2s[128], o2s[128];
  __shared__ float wc[128];
  __shared__ float patch[256];
  __shared__ int keptL[256];
  __shared__ float keptS[256];
  __shared__ float gateL[256];
  __shared__ __align__(16) float xk[128];
  __shared__ __align__(16) float pooled[128];
  __shared__ int nkept;
  const int t = threadIdx.x;
  const int g = blockIdx.x >> 2, c = blockIdx.x & 3;
  if(t<128){
    float mu = bns0[t]*(1.0f/NN);
    float var = bnq0[t]*(1.0f/NN) - mu*mu;
    float sv = g0[t]*rsqrtf(var+1e-5f);
    sc0s[t]=sv; of0s[t]=b0bn[t]-mu*sv;
    float mu1 = bnsA[t]*(1.0f/NN);
    float var1 = bnqA[t]*(1.0f/NN) - mu1*mu1;
    float s1 = g1v[t]*rsqrtf(var1+1e-5f);
    s1s[t]=s1; o1s[t]=b1v[t]-mu1*s1;
    float mu2 = bnsB[t]*(1.0f/NN);
    float var2 = bnqB[t]*(1.0f/NN) - mu2*mu2;
    float s2 = g2v[t]*rsqrtf(var2+1e-5f);
    s2s[t]=s2; o2s[t]=b2v[t]-mu2*s2;
    wc[t] = pwc[c*128+t];
  }
  patch[t]=0.f;
  __syncthreads();
  int total1 = *cnt1; if(total1 > CAP) total1 = CAP;
  for(int i=t; i<total1; i+=256){
    int wv = wl1[i];
    int n = wv & 0xFFFF, hp = wv>>16;
    if((n>>8)==g){
      float d=0.f;
      for(int l=0;l<32;l++){
        int j = hp*32+l;
        d += new2c[(size_t)i*32+l]*s2s[j]*wc[j];
      }
      atomicAdd(&patch[n&255], 0.25f*d);
    }
  }
  __syncthreads();
  const int n = g*256 + t;
  float sc = pre2[n*4 + c] + patch[t];
  float m = blockMax4(sc, red);
  float e = expf(sc-m);
  float ssum = blockSum4(e, red);
  float sm = e/(ssum+1e-16f);
  float smax = blockMax4(sm, red);
  float thr = fminf(smax - 1e-7f, 0.8f);
  if(t==0) nkept = 0;
  __syncthreads();
  if(sm > thr){
    int p = atomicAdd(&nkept,1);
    keptL[p]=t; keptS[p]=sm;
  }
  __syncthreads();
  const int K = nkept;
  for(int k=0;k<K;k++){
    int ln = keptL[k]; float sv = keptS[k];
    int nn = g*256 + ln;
    if(t<32){
      float4 c0 = ((const float4*)cur0)[nn*32 + t];
      float4 s0l = *(const float4*)&sc0s[t*4];
      float4 o0l = *(const float4*)&of0s[t*4];
      float4 s1l = *(const float4*)&s1s[t*4];
      float4 o1l = *(const float4*)&o1s[t*4];
      float4 s2l = *(const float4*)&s2s[t*4];
      float4 o2l = *(const float4*)&o2s[t*4];
      int hb = t>>3;
      float4 v1;
      v1.x = 0.5f*(s0l.x*c0.x+o0l.x) + 0.25f*o1l.x;
      v1.y = 0.5f*(s0l.y*c0.y+o0l.y) + 0.25f*o1l.y;
      v1.z = 0.5f*(s0l.z*c0.z+o0l.z) + 0.25f*o1l.z;
      v1.w = 0.5f*(s0l.w*c0.w+o0l.w) + 0.25f*o1l.w;
      if((keep0[nn]>>hb)&1){
        float4 nv = ((const float4*)(new1c + (size_t)idx0[nn*4+hb]*32))[t&7];
        v1.x += 0.25f*s1l.x*nv.x; v1.y += 0.25f*s1l.y*nv.y;
        v1.z += 0.25f*s1l.z*nv.z; v1.w += 0.25f*s1l.w*nv.w;
      }
      float4 v2;
      v2.x = 0.5f*v1.x + 0.25f*o2l.x;
      v2.y = 0.5f*v1.y + 0.25f*o2l.y;
      v2.z = 0.5f*v1.z + 0.25f*o2l.z;
      v2.w = 0.5f*v1.w + 0.25f*o2l.w;
      if((keep1[nn]>>hb)&1){
        float4 nv = ((const float4*)(new2c + (size_t)idx1[nn*4+hb]*32))[t&7];
        v2.x += 0.25f*s2l.x*nv.x; v2.y += 0.25f*s2l.y*nv.y;
        v2.z += 0.25f*s2l.z*nv.z; v2.w += 0.25f*s2l.w*nv.w;
      }
      v2.x*=sv; v2.y*=sv; v2.z*=sv; v2.w*=sv;
      *(float4*)&xk[t*4] = v2;
    }
    __syncthreads();
    float part = 0.f;
    if(t<128){
      const float* W = gW1 + (size_t)c*16384 + (size_t)t*128;
      float a = gb1[c*128+t];
      for(int f=0;f<32;f++){
        float4 xv = *(const float4*)&xk[f*4];
        float4 wv = ((const float4*)W)[f];
        a += xv.x*wv.x + xv.y*wv.y + xv.z*wv.z + xv.w*wv.w;
      }
      part = lrelu(a) * gW2[c*128+t];
    }
    float gs = blockSum4(part, red);
    if(t==0) gateL[k] = gs + gb2[c];
    __syncthreads();
  }
  float gv = (t<K)? gateL[t] : -INFINITY;
  float gm = blockMax4(gv, red);
  float ge = (t<K)? expf(gv-gm) : 0.f;
  float gsum = blockSum4(ge, red);
  if(t<K) gateL[t] = ge/(gsum+1e-16f);
  __syncthreads();
  if(t<128){
    int hb = t>>5, l = t&31;
    float acc = 0.f;
    for(int k=0;k<K;k++){
      int nn = g*256 + keptL[k];
      float c0 = cur0[(size_t)nn*128 + t];
      float v1 = 0.5f*(sc0s[t]*c0 + of0s[t]) + 0.25f*o1s[t];
      if((keep0[nn]>>hb)&1) v1 += 0.25f*s1s[t]*new1c[(size_t)idx0[nn*4+hb]*32 + l];
      float v2 = 0.5f*v1 + 0.25f*o2s[t];
      if((keep1[nn]>>hb)&1) v2 += 0.25f*s2s[t]*new2c[(size_t)idx1[nn*4+hb]*32 + l];
      acc += gateL[k]*keptS[k]*v2;
    }
    pooled[t]=acc;
  }
  __syncthreads();
  float part2=0.f;
  if(t<128){
    const float* F = fW1 + (size_t)c*16384 + (size_t)t*128;
    float a = fb1[c*128+t];
    for(int f=0;f<32;f++){
      float4 xv = *(const float4*)&pooled[f*4];
      float4 wv = ((const float4*)F)[f];
      a += xv.x*wv.x + xv.y*wv.y + xv.z*wv.z + xv.w*wv.w;
    }
    part2 = lrelu(a) * fW2[c*128+t];
  }
  float ysum = blockSum4(part2, red);
  if(t==0) yws[g*4+c] = ysum + fb2[c];
}

// ---------- final per-graph log_softmax over 4 class logits ----------
__global__ __launch_bounds__(256) void k_clsfin(const float* __restrict__ yws,
                                                float* __restrict__ out){
  const int g = threadIdx.x;
  float4 y = ((const float4*)yws)[g];
  float m = fmaxf(fmaxf(y.x,y.y), fmaxf(y.z,y.w));
  float l = logf(expf(y.x-m)+expf(y.y-m)+expf(y.z-m)+expf(y.w-m));
  ((float4*)out)[g] = make_float4(y.x-m-l, y.y-m-l, y.z-m-l, y.w-m-l);
}

extern "C" void kernel_launch(void* const* d_in, const int* in_sizes, int n_in,
                              void* d_out, int out_size, void* d_ws, size_t ws_size,
                              hipStream_t stream){
  (void)in_sizes; (void)n_in; (void)out_size; (void)ws_size;
  const float* x     = (const float*)d_in[0];
  const int*   ei    = (const int*)d_in[1];
  const float* Wrel0 = (const float*)d_in[3];
  const float* Wroot0= (const float*)d_in[4];
  const float* b0    = (const float*)d_in[5];
  const float* bn0g  = (const float*)d_in[6];
  const float* bn0b  = (const float*)d_in[7];
  const float* bpw   = (const float*)d_in[8];
  const float* bWrel = (const float*)d_in[9];
  const float* bWroot= (const float*)d_in[10];
  const float* bbv   = (const float*)d_in[11];
  const float* bbng  = (const float*)d_in[12];
  const float* bbnb  = (const float*)d_in[13];
  const float* cpw   = (const float*)d_in[14];
  const float* gW1   = (const float*)d_in[15];
  const float* gb1   = (const float*)d_in[16];
  const float* gW2   = (const float*)d_in[17];
  const float* gb2   = (const float*)d_in[18];
  const float* fW1   = (const float*)d_in[19];
  const float* fb1   = (const float*)d_in[20];
  const float* fW2   = (const float*)d_in[21];
  const float* fb2   = (const float*)d_in[22];

  char* ws = (char*)d_ws;
  float* cur0  = (float*)(ws + 0);                  // 33.55 MB
  float* new1c = (float*)(ws + 33554432ull);        // 16.78 MB (CAP*32 floats)
  float* new2c = (float*)(ws + 50331648ull);        // 16.78 MB (aliases agg0)
  float* agg0  = new2c;                             // dead before new2c written
  int*   csr   = (int*)(ws + 67108864ull);          // 2 MB
  float* scores0=(float*)(ws + 69206016ull);        // 1 MB (sm4_0 aliases)
  float* sm40  = scores0;
  float* pre1  = (float*)(ws + 70254592ull);        // 1 MB (sm4_1 aliases)
  float* sm41  = pre1;
  float* pre2  = (float*)(ws + 71303168ull);        // 1 MB
  int*   wl0   = (int*)(ws + 72351744ull);          // 512 KB
  int*   wl1   = (int*)(ws + 72876032ull);          // 512 KB
  int*   offs  = (int*)(ws + 73400320ull);          // 256 KB + 4
  int*   cursor= (int*)(ws + 73666560ull);          // 256 KB
  unsigned char* keep0 = (unsigned char*)(ws + 73928704ull); // 64 KB
  unsigned char* keep1 = (unsigned char*)(ws + 73994240ull); // 64 KB
  int*   idx0  = (int*)(ws + 74059776ull);          // 1 MB
  int*   idx1  = (int*)(ws + 75108352ull);          // 1 MB
  char*  Z     = ws + 76156928ull;                  // zero-init region
  int*   deg   = (int*)Z;                           // 256 KB
  float* bnsum0= (float*)(Z + 262144);
  float* bnsq0 = (float*)(Z + 262656);
  float* bnA   = (float*)(Z + 263168);
  float* bqA   = (float*)(Z + 263680);
  float* bnB   = (float*)(Z + 264192);
  float* bqB   = (float*)(Z + 264704);
  int*   cnt0  = (int*)(Z + 265216);
  int*   cnt1  = (int*)(Z + 265220);
  float* yws   = (float*)(Z + 266240);              // 4 KB

  hipMemsetAsync(Z, 0, 270336, stream);
  hipMemsetAsync(idx0, 0xFF, 2097152, stream);      // idx0+idx1 contiguous

  // CSR by dst
  k_count  <<<2048,256,0,stream>>>(ei, deg);
  k_scan   <<<1,1024,0,stream>>>(deg, offs, cursor);
  k_scatter<<<2048,256,0,stream>>>(ei, cursor, csr);

  // conv0 -> lrelu (+ fused bn0 stats; bn0 apply stays folded downstream)
  k_agg0    <<<4096,256,0,stream>>>(x, offs, csr, agg0);
  k_conv0mm <<<512,256,0,stream>>>(agg0, x, Wrel0, Wroot0, b0, cur0, bnsum0, bnsq0);

  // single pass: scores for pool0 + pre-scores for pool1/cls
  k_scores<<<8192,256,0,stream>>>(cur0, bnsum0, bnsq0, bn0g,
                                  bpw, bpw + 512, cpw, scores0, pre1, pre2);

  // pool layer 0 select
  k_poolsel<<<256,256,0,stream>>>(scores0, 0.7f, sm40, keep0, cnt0, wl0, idx0);

  // layer-0 conv on kept items
  k_blockconv0<<<256,256,0,stream>>>(cur0, offs, csr, keep0, sm40, cnt0, wl0,
                                     bWrel, bWroot, bbv, new1c, bnA, bqA,
                                     bnsum0, bnsq0, bn0g, bn0b);

  // pool layer 1 select (patches pre1 with layer-1 corr, pre2 partially)
  k_poolsel1<<<256,256,0,stream>>>(pre1, pre2, cnt0, wl0, new1c,
                                   bnA, bqA, bbng,
                                   bpw + 512, cpw,
                                   0.7f, sm41, keep1, cnt1, wl1, idx1);

  // layer-1 conv on kept items (rows reconstructed)
  k_blockconv1<<<256,256,0,stream>>>(cur0, offs, csr, keep0, idx0, new1c,
                                     keep1, sm41, cnt1, wl1,
                                     bWrel + 16384, bWroot + 16384, bbv + 128,
                                     new2c, bnB, bqB,
                                     bnsum0, bnsq0, bn0g, bn0b,
                                     bnA, bqA, bbng, bbnb);

  // classification heads (patch pre2 with layer-2 corr in-block)
  k_cls2<<<1024,256,0,stream>>>(cur0, keep0, idx0, new1c, keep1, idx1, new2c,
                                pre2, cnt1, wl1, cpw,
                                bnsum0, bnsq0, bn0g, bn0b,
                                bnA, bqA, bbng, bbnb,
                                bnB, bqB, bbng + 128, bbnb + 128,
                                gW1, gb1, gW2, gb2, fW1, fb1, fW2, fb2, yws);
  k_clsfin<<<1,256,0,stream>>>(yws, (float*)d_out);
}

// Round 10
// 379.485 us; speedup vs baseline: 1.2740x; 1.0120x over previous
//
#include <hip/hip_runtime.h>
#include <math.h>

#define NN 65536      // nodes
#define NE 524288     // edges
#define NG 256        // graphs (256 contiguous nodes each)
#define SLOPE 0.01f
#define CAP 131072    // worklist capacity per layer (typ. ~1k items)

__device__ __forceinline__ float lrelu(float v){ return v > 0.f ? v : SLOPE*v; }

// ---------- block reductions (256-thread blocks = 4 waves) ----------
__device__ __forceinline__ float blockMax4(float v, float* s4){
  #pragma unroll
  for(int o=32;o>0;o>>=1) v = fmaxf(v, __shfl_down(v, o, 64));
  int t = threadIdx.x;
  __syncthreads();
  if((t&63)==0) s4[t>>6] = v;
  __syncthreads();
  return fmaxf(fmaxf(s4[0], s4[1]), fmaxf(s4[2], s4[3]));
}
__device__ __forceinline__ float blockSum4(float v, float* s4){
  #pragma unroll
  for(int o=32;o>0;o>>=1) v += __shfl_down(v, o, 64);
  int t = threadIdx.x;
  __syncthreads();
  if((t&63)==0) s4[t>>6] = v;
  __syncthreads();
  return (s4[0]+s4[1])+(s4[2]+s4[3]);
}

// ---------- CSR build (by dst) ----------
__global__ __launch_bounds__(256) void k_count(const int* __restrict__ ei, int* __restrict__ deg){
  int e = blockIdx.x*256 + threadIdx.x;
  if(e < NE) atomicAdd(&deg[ei[NE + e]], 1);
}

__global__ __launch_bounds__(1024) void k_scan(const int* __restrict__ deg,
      int* __restrict__ offs, int* __restrict__ cursor){
  __shared__ int part[1024];
  int t = threadIdx.x;
  const int4* d4 = (const int4*)(deg + t*64);
  int4 buf[16];
  int s=0;
  #pragma unroll
  for(int i=0;i<16;i++){ buf[i]=d4[i]; s += buf[i].x+buf[i].y+buf[i].z+buf[i].w; }
  part[t]=s;
  __syncthreads();
  for(int off=1; off<1024; off<<=1){
    int v = (t>=off)? part[t-off] : 0;
    __syncthreads();
    part[t] += v;
    __syncthreads();
  }
  int run = (t==0)? 0 : part[t-1];
  #pragma unroll
  for(int i=0;i<16;i++){
    int4 d = buf[i];
    int4 o;
    o.x = run; run += d.x;
    o.y = run; run += d.y;
    o.z = run; run += d.z;
    o.w = run; run += d.w;
    ((int4*)(offs + t*64))[i] = o;
    ((int4*)(cursor + t*64))[i] = o;
  }
  if(t==1023) offs[NN] = run;
}

__global__ __launch_bounds__(256) void k_scatter(const int* __restrict__ ei,
      int* __restrict__ cursor, int* __restrict__ csr){
  int e = blockIdx.x*256 + threadIdx.x;
  if(e < NE){
    int d = ei[NE + e];
    int p = atomicAdd(&cursor[d], 1);
    csr[p] = ei[e];
  }
}

// ---------- conv0: agg[i] = max over in-edges of x[src], else 0 ----------
__global__ __launch_bounds__(256) void k_agg0(const float* __restrict__ x,
    const int* __restrict__ offs, const int* __restrict__ csr, float* __restrict__ agg0){
  int tid = blockIdx.x*256 + threadIdx.x;
  int node = tid>>4, q = tid&15;
  int e0 = offs[node], e1 = offs[node+1];
  float4 acc = make_float4(0.f,0.f,0.f,0.f);
  if(e0 < e1){
    acc = make_float4(-INFINITY,-INFINITY,-INFINITY,-INFINITY);
    int e = e0;
    for(; e+7 < e1; e += 8){
      int si[8];
      #pragma unroll
      for(int u=0;u<8;u++) si[u] = csr[e+u];
      float4 v[8];
      #pragma unroll
      for(int u=0;u<8;u++) v[u] = ((const float4*)x)[si[u]*16 + q];
      #pragma unroll
      for(int u=0;u<8;u++){
        acc.x=fmaxf(acc.x,v[u].x); acc.y=fmaxf(acc.y,v[u].y);
        acc.z=fmaxf(acc.z,v[u].z); acc.w=fmaxf(acc.w,v[u].w);
      }
    }
    for(; e < e1; e++){
      int s0 = csr[e];
      float4 v0 = ((const float4*)x)[s0*16 + q];
      acc.x=fmaxf(acc.x,v0.x); acc.y=fmaxf(acc.y,v0.y);
      acc.z=fmaxf(acc.z,v0.z); acc.w=fmaxf(acc.w,v0.w);
    }
  }
  ((float4*)agg0)[node*16 + q] = acc;
}

// ---------- conv0 matmul: cur0 = lrelu([agg0|x] @ [Wrel|Wroot]^T + b0) ----------
// r10: W tiles NOT staged in LDS — every block reads the same 64 KB of weights,
// 16 lanes/address broadcast, L2-resident (32 MB aggregate ≈ 1 µs of L2 BW).
// Halves LDS traffic (VALU-bound now) and LDS footprint (32 KB), and shrinks
// the RA's live set (r5-r9: acc half-spilled at 88 VGPR + 16 MB scratch writes).
__global__ __launch_bounds__(256, 2) void k_conv0mm(
    const float* __restrict__ agg0, const float* __restrict__ x,
    const float* __restrict__ Wrel, const float* __restrict__ Wroot,
    const float* __restrict__ b0, float* __restrict__ cur,
    float* __restrict__ bnsum, float* __restrict__ bnsq){
  __shared__ float4 As[2048];   // 32 KB
  const int t = threadIdx.x;
  const int tn = t & 15;
  const int tc = t >> 4;
  float acc[8][8];
  #pragma unroll
  for(int i=0;i<8;i++)
    #pragma unroll
    for(int j=0;j<8;j++) acc[i][j]=0.f;

  const size_t tileoff = (size_t)blockIdx.x * 8192;
  #pragma unroll 1
  for(int ch=0; ch<2; ch++){
    const float4* gA = (const float4*)((ch==0? agg0 : x) + tileoff);
    const float4* gW = (const float4*)(ch==0? Wrel : Wroot);
    __syncthreads();
    #pragma unroll
    for(int i=0;i<8;i++){
      int idx = t + i*256;
      int n = idx>>4, k4 = idx&15;
      As[n*16 + ((k4 + (n>>3))&15)] = gA[idx];
    }
    __syncthreads();
    #pragma unroll 1
    for(int k4=0;k4<16;k4++){
      float4 a4[8];
      #pragma unroll
      for(int i=0;i<8;i++) a4[i] = As[(tn*8+i)*16 + ((k4+tn)&15)];
      #pragma unroll
      for(int j=0;j<8;j++){
        float4 w4 = gW[(tc*8+j)*16 + k4];     // 16-lane broadcast, L2-hit
        #pragma unroll
        for(int i=0;i<8;i++){
          acc[i][j] = fmaf(a4[i].x, w4.x, acc[i][j]);
          acc[i][j] = fmaf(a4[i].y, w4.y, acc[i][j]);
          acc[i][j] = fmaf(a4[i].z, w4.z, acc[i][j]);
          acc[i][j] = fmaf(a4[i].w, w4.w, acc[i][j]);
        }
      }
    }
  }

  float bj[8];
  #pragma unroll
  for(int j=0;j<8;j++) bj[j] = b0[tc*8+j];
  float cs[8], cq[8];
  #pragma unroll
  for(int j=0;j<8;j++){ cs[j]=0.f; cq[j]=0.f; }
  const int nbase = blockIdx.x*128;
  #pragma unroll
  for(int i=0;i<8;i++){
    int node = nbase + tn*8 + i;
    float v[8];
    #pragma unroll
    for(int j=0;j<8;j++){
      v[j] = lrelu(acc[i][j] + bj[j]);
      cs[j] += v[j]; cq[j] += v[j]*v[j];
    }
    float4 o0 = make_float4(v[0],v[1],v[2],v[3]);
    float4 o1 = make_float4(v[4],v[5],v[6],v[7]);
    ((float4*)cur)[node*32 + tc*2 + 0] = o0;
    ((float4*)cur)[node*32 + tc*2 + 1] = o1;
  }
  __syncthreads();
  float* reds = (float*)As;          // 2048 floats
  float* redq = ((float*)As) + 2048; // 2048 floats (As = 8192 floats total)
  #pragma unroll
  for(int j=0;j<8;j++){
    reds[(tc*8+j)*16 + tn] = cs[j];
    redq[(tc*8+j)*16 + tn] = cq[j];
  }
  __syncthreads();
  if(t<128){
    float S=0.f, Q=0.f;
    #pragma unroll
    for(int i=0;i<16;i++){ S += reds[t*16+i]; Q += redq[t*16+i]; }
    atomicAdd(&bnsum[t], S);
    atomicAdd(&bnsq[t], Q);
  }
}

// ---------- one pass over cur0: scores for pool0, pool1, cls (affine fold) ----------
__global__ __launch_bounds__(256) void k_scores(const float* __restrict__ cur0,
    const float* __restrict__ bns0, const float* __restrict__ bnq0,
    const float* __restrict__ g0,
    const float* __restrict__ pw0, const float* __restrict__ pw1,
    const float* __restrict__ pwc,
    float* __restrict__ scores0, float* __restrict__ pre1, float* __restrict__ pre2){
  __shared__ __align__(16) float w[12][128];
  __shared__ float sc0s[128];
  const int t = threadIdx.x;
  if(t<128){
    float mu = bns0[t]*(1.0f/NN);
    float var = bnq0[t]*(1.0f/NN) - mu*mu;
    sc0s[t] = g0[t]*rsqrtf(var+1e-5f);
  }
  __syncthreads();
  for(int i=t;i<512;i+=256){
    int h=i>>7, j=i&127;
    float s = sc0s[j];
    w[h][j]   = pw0[i]*s;
    w[4+h][j] = pw1[i]*(0.5f*s);
    w[8+h][j] = pwc[i]*(0.25f*s);
  }
  __syncthreads();
  const int tid = blockIdx.x*256 + t;
  const int n = tid>>5, k = tid&31;
  float4 v = ((const float4*)cur0)[tid];
  float a[12];
  #pragma unroll
  for(int q=0;q<12;q++){
    float4 wv = *(const float4*)&w[q][k*4];
    a[q] = v.x*wv.x + v.y*wv.y + v.z*wv.z + v.w*wv.w;
  }
  #pragma unroll
  for(int o=16;o>0;o>>=1){
    #pragma unroll
    for(int q=0;q<12;q++) a[q] += __shfl_down(a[q], o, 32);
  }
  if(k==0){
    ((float4*)scores0)[n] = make_float4(a[0],a[1],a[2],a[3]);
    ((float4*)pre1)[n]    = make_float4(a[4],a[5],a[6],a[7]);
    ((float4*)pre2)[n]    = make_float4(a[8],a[9],a[10],a[11]);
  }
}

// ---------- pool select layer 0: wave-per-head, barrier-free (r10) ----------
// idxP plane: idxP[h*NN+n] = worklist slot if kept else -1 (always written —
// replaces keep bitmask + idx array + their memset). sm4 aliases scores:
// wave h only touches component h -> no cross-wave hazard, no barrier.
__global__ __launch_bounds__(256) void k_poolselW(const float* __restrict__ scores,
    float minscore, float* __restrict__ sm4, int* __restrict__ cnt,
    int* __restrict__ wl, int* __restrict__ idxP){
  const int t = threadIdx.x, g = blockIdx.x;
  const int h = t>>6, l = t&63;
  const int n0 = g*256;
  float s[4];
  #pragma unroll
  for(int i=0;i<4;i++) s[i] = scores[(size_t)(n0 + l + i*64)*4 + h];
  float m = fmaxf(fmaxf(s[0],s[1]),fmaxf(s[2],s[3]));
  #pragma unroll
  for(int o=32;o>0;o>>=1) m = fmaxf(m, __shfl_xor(m, o, 64));
  float e[4], es=0.f;
  #pragma unroll
  for(int i=0;i<4;i++){ e[i]=expf(s[i]-m); es+=e[i]; }
  #pragma unroll
  for(int o=32;o>0;o>>=1) es += __shfl_xor(es, o, 64);
  float inv = 1.f/(es+1e-16f);
  float sm[4];
  float mx = -INFINITY;
  #pragma unroll
  for(int i=0;i<4;i++){ sm[i]=e[i]*inv; mx=fmaxf(mx,sm[i]); }
  #pragma unroll
  for(int o=32;o>0;o>>=1) mx = fmaxf(mx, __shfl_xor(mx, o, 64));
  float thr = fminf(mx - 1e-7f, minscore);
  #pragma unroll
  for(int i=0;i<4;i++){
    int n = n0 + l + i*64;
    sm4[(size_t)n*4 + h] = sm[i];
    int slot = -1;
    if(sm[i] > thr){
      int p = atomicAdd(cnt, 1);
      if(p < CAP){ slot = p; wl[p] = (h<<16) | n; }
    }
    idxP[(size_t)h*NN + n] = slot;
  }
}

// ---------- layer-0 GraphConv(max) on kept items (rows = bn0(cur0)) ----------
__global__ __launch_bounds__(256) void k_blockconv0(const float* __restrict__ cur0,
    const int* __restrict__ offs, const int* __restrict__ csr,
    const int* __restrict__ idxP, const float* __restrict__ sm4,
    const int* __restrict__ cnt, const int* __restrict__ wl,
    const float* __restrict__ Wrel, const float* __restrict__ Wroot,
    const float* __restrict__ bias,
    float* __restrict__ new1c, float* __restrict__ bnsum, float* __restrict__ bnsq,
    const float* __restrict__ bns0, const float* __restrict__ bnq0,
    const float* __restrict__ g0, const float* __restrict__ b0bn){
  __shared__ __align__(16) float aggs[8][128];
  __shared__ __align__(16) float xps[8][128];
  __shared__ __align__(16) float scv[128];
  __shared__ __align__(16) float ofv[128];
  const int t = threadIdx.x, grp = t>>5, lane = t&31;
  if(t<128){
    float mu = bns0[t]*(1.0f/NN);
    float var = bnq0[t]*(1.0f/NN) - mu*mu;
    float sv = g0[t]*rsqrtf(var+1e-5f);
    scv[t]=sv; ofv[t]=b0bn[t]-mu*sv;
  }
  __syncthreads();
  const float4 s4l = *(const float4*)&scv[lane*4];
  const float4 o4l = *(const float4*)&ofv[lane*4];
  int total = *cnt; if(total > CAP) total = CAP;
  for(int item = blockIdx.x*8 + grp; item < total; item += gridDim.x*8){
    const int wv = wl[item];
    const int h = wv>>16, n = wv & 0xFFFF;
    const size_t hn = (size_t)h*NN;
    const float smn = sm4[(size_t)n*4+h];
    const int e0 = offs[n], e1 = offs[n+1];
    float4 acc = make_float4(-INFINITY,-INFINITY,-INFINITY,-INFINITY);
    bool any = false;
    for(int e=e0;e<e1;e++){
      int s = csr[e];
      if(idxP[hn + s] >= 0){
        any = true;
        float sv = sm4[(size_t)s*4+h];
        float4 v = ((const float4*)cur0)[s*32 + lane];
        v.x = (v.x*s4l.x + o4l.x)*sv; v.y = (v.y*s4l.y + o4l.y)*sv;
        v.z = (v.z*s4l.z + o4l.z)*sv; v.w = (v.w*s4l.w + o4l.w)*sv;
        acc.x = fmaxf(acc.x, v.x); acc.y = fmaxf(acc.y, v.y);
        acc.z = fmaxf(acc.z, v.z); acc.w = fmaxf(acc.w, v.w);
      }
    }
    if(!any) acc = make_float4(0.f,0.f,0.f,0.f);
    *(float4*)&aggs[grp][lane*4] = acc;
    float4 xv = ((const float4*)cur0)[n*32 + lane];
    xv.x = (xv.x*s4l.x + o4l.x)*smn; xv.y = (xv.y*s4l.y + o4l.y)*smn;
    xv.z = (xv.z*s4l.z + o4l.z)*smn; xv.w = (xv.w*s4l.w + o4l.w)*smn;
    *(float4*)&xps[grp][lane*4] = xv;
    // half-wave group: LDS write->read program-ordered within the wave
    const float* Wr = Wrel  + (size_t)(h*32+lane)*128;
    const float* Wo = Wroot + (size_t)(h*32+lane)*128;
    float o = bias[h*32+lane];
    for(int k=0;k<32;k++){
      float4 a  = *(const float4*)&aggs[grp][k*4];
      float4 xx = *(const float4*)&xps[grp][k*4];
      float4 wr = ((const float4*)Wr)[k];
      float4 wo = ((const float4*)Wo)[k];
      o += a.x*wr.x + a.y*wr.y + a.z*wr.z + a.w*wr.w;
      o += xx.x*wo.x + xx.y*wo.y + xx.z*wo.z + xx.w*wo.w;
    }
    o = lrelu(o);
    new1c[(size_t)item*32 + lane] = o;
    atomicAdd(&bnsum[h*32+lane], o);
    atomicAdd(&bnsq[h*32+lane], o*o);
  }
}

// ---------- pool select layer 1: patch phase (block-wide) + wave-per-head select ----------
__global__ __launch_bounds__(256) void k_poolsel1(
    const float* __restrict__ pre1, float* __restrict__ pre2,
    const int* __restrict__ cnt0, const int* __restrict__ wl0,
    const float* __restrict__ new1c,
    const float* __restrict__ bnsA, const float* __restrict__ bnqA,
    const float* __restrict__ g1v,
    const float* __restrict__ pw1, const float* __restrict__ pwc,
    float minscore, float* __restrict__ sm4out,
    int* __restrict__ cnt1, int* __restrict__ wl1, int* __restrict__ idx1P){
  __shared__ float s1s[128];
  __shared__ __align__(16) float w1s[4][128];
  __shared__ __align__(16) float wcs[4][128];
  __shared__ float patch1[256][4];
  const int t = threadIdx.x, g = blockIdx.x;
  if(t<128){
    float mu = bnsA[t]*(1.0f/NN);
    float var = bnqA[t]*(1.0f/NN) - mu*mu;
    s1s[t] = g1v[t]*rsqrtf(var+1e-5f);
  }
  for(int i=t;i<512;i+=256){ w1s[i>>7][i&127]=pw1[i]; wcs[i>>7][i&127]=pwc[i]; }
  #pragma unroll
  for(int h=0;h<4;h++) patch1[t][h]=0.f;
  __syncthreads();
  int total0 = *cnt0; if(total0 > CAP) total0 = CAP;
  for(int i=t; i<total0; i+=256){
    int wv = wl0[i];
    int n = wv & 0xFFFF, hp = wv>>16;
    if((n>>8)==g){
      int nl = n & 255;
      float d[4]={0.f,0.f,0.f,0.f}, d2[4]={0.f,0.f,0.f,0.f};
      for(int l=0;l<32;l++){
        int j = hp*32+l;
        float base = new1c[(size_t)i*32+l] * s1s[j];
        #pragma unroll
        for(int h=0;h<4;h++){ d[h]+=base*w1s[h][j]; d2[h]+=base*wcs[h][j]; }
      }
      #pragma unroll
      for(int h=0;h<4;h++){
        atomicAdd(&patch1[nl][h], 0.25f*d[h]);
        atomicAdd(&pre2[n*4+h], 0.125f*d2[h]);
      }
    }
  }
  __syncthreads();
  // wave-per-head selection (sm4out aliases pre1: component-h only, safe)
  const int h = t>>6, l = t&63;
  const int n0 = g*256;
  float s[4];
  #pragma unroll
  for(int i=0;i<4;i++){
    int nl = l + i*64;
    s[i] = pre1[(size_t)(n0+nl)*4 + h] + patch1[nl][h];
  }
  float m = fmaxf(fmaxf(s[0],s[1]),fmaxf(s[2],s[3]));
  #pragma unroll
  for(int o=32;o>0;o>>=1) m = fmaxf(m, __shfl_xor(m, o, 64));
  float e[4], es=0.f;
  #pragma unroll
  for(int i=0;i<4;i++){ e[i]=expf(s[i]-m); es+=e[i]; }
  #pragma unroll
  for(int o=32;o>0;o>>=1) es += __shfl_xor(es, o, 64);
  float inv = 1.f/(es+1e-16f);
  float sm[4];
  float mx = -INFINITY;
  #pragma unroll
  for(int i=0;i<4;i++){ sm[i]=e[i]*inv; mx=fmaxf(mx,sm[i]); }
  #pragma unroll
  for(int o=32;o>0;o>>=1) mx = fmaxf(mx, __shfl_xor(mx, o, 64));
  float thr = fminf(mx - 1e-7f, minscore);
  #pragma unroll
  for(int i=0;i<4;i++){
    int n = n0 + l + i*64;
    sm4out[(size_t)n*4 + h] = sm[i];
    int slot = -1;
    if(sm[i] > thr){
      int p = atomicAdd(cnt1, 1);
      if(p < CAP){ slot = p; wl1[p] = (h<<16) | n; }
    }
    idx1P[(size_t)h*NN + n] = slot;
  }
}

// ---------- layer-1 GraphConv(max): rows reconstructed from cur0 + new1c ----------
__global__ __launch_bounds__(256) void k_blockconv1(const float* __restrict__ cur0,
    const int* __restrict__ offs, const int* __restrict__ csr,
    const int* __restrict__ idx0P, const float* __restrict__ new1c,
    const int* __restrict__ idx1P, const float* __restrict__ sm41,
    const int* __restrict__ cnt1, const int* __restrict__ wl1,
    const float* __restrict__ Wrel, const float* __restrict__ Wroot,
    const float* __restrict__ bias,
    float* __restrict__ new2c, float* __restrict__ bnsum, float* __restrict__ bnsq,
    const float* __restrict__ bns0, const float* __restrict__ bnq0,
    const float* __restrict__ g0, const float* __restrict__ b0bn,
    const float* __restrict__ bnsA, const float* __restrict__ bnqA,
    const float* __restrict__ g1v, const float* __restrict__ b1v){
  __shared__ __align__(16) float aggs[8][128];
  __shared__ __align__(16) float xps[8][128];
  __shared__ __align__(16) float sc0s[128], of0s[128], s1s[128], o1s[128];
  const int t = threadIdx.x, grp = t>>5, lane = t&31;
  if(t<128){
    float mu = bns0[t]*(1.0f/NN);
    float var = bnq0[t]*(1.0f/NN) - mu*mu;
    float sv = g0[t]*rsqrtf(var+1e-5f);
    sc0s[t]=sv; of0s[t]=b0bn[t]-mu*sv;
    float mu1 = bnsA[t]*(1.0f/NN);
    float var1 = bnqA[t]*(1.0f/NN) - mu1*mu1;
    float s1 = g1v[t]*rsqrtf(var1+1e-5f);
    s1s[t]=s1; o1s[t]=b1v[t]-mu1*s1;
  }
  __syncthreads();
  const float4 s0l = *(const float4*)&sc0s[lane*4];
  const float4 o0l = *(const float4*)&of0s[lane*4];
  const float4 s1l = *(const float4*)&s1s[lane*4];
  const float4 o1l = *(const float4*)&o1s[lane*4];
  const int hb = lane>>3;
  const size_t hbn = (size_t)hb*NN;
  int total = *cnt1; if(total > CAP) total = CAP;
  for(int item = blockIdx.x*8 + grp; item < total; item += gridDim.x*8){
    const int wv = wl1[item];
    const int h = wv>>16, n = wv & 0xFFFF;
    const size_t hn = (size_t)h*NN;
    const float smn = sm41[(size_t)n*4+h];
    const int e0 = offs[n], e1 = offs[n+1];
    float4 acc = make_float4(-INFINITY,-INFINITY,-INFINITY,-INFINITY);
    bool any = false;
    for(int e=e0;e<e1;e++){
      int s = csr[e];
      if(idx1P[hn + s] >= 0){
        any = true;
        float sv = sm41[(size_t)s*4+h];
        float4 c0 = ((const float4*)cur0)[s*32 + lane];
        float4 v;
        v.x = 0.5f*(s0l.x*c0.x+o0l.x) + 0.25f*o1l.x;
        v.y = 0.5f*(s0l.y*c0.y+o0l.y) + 0.25f*o1l.y;
        v.z = 0.5f*(s0l.z*c0.z+o0l.z) + 0.25f*o1l.z;
        v.w = 0.5f*(s0l.w*c0.w+o0l.w) + 0.25f*o1l.w;
        int i0 = idx0P[hbn + s];
        if(i0 >= 0){
          float4 nv = ((const float4*)(new1c + (size_t)i0*32))[lane&7];
          v.x += 0.25f*s1l.x*nv.x; v.y += 0.25f*s1l.y*nv.y;
          v.z += 0.25f*s1l.z*nv.z; v.w += 0.25f*s1l.w*nv.w;
        }
        v.x*=sv; v.y*=sv; v.z*=sv; v.w*=sv;
        acc.x = fmaxf(acc.x, v.x); acc.y = fmaxf(acc.y, v.y);
        acc.z = fmaxf(acc.z, v.z); acc.w = fmaxf(acc.w, v.w);
      }
    }
    if(!any) acc = make_float4(0.f,0.f,0.f,0.f);
    *(float4*)&aggs[grp][lane*4] = acc;
    {
      float4 c0 = ((const float4*)cur0)[n*32 + lane];
      float4 v;
      v.x = 0.5f*(s0l.x*c0.x+o0l.x) + 0.25f*o1l.x;
      v.y = 0.5f*(s0l.y*c0.y+o0l.y) + 0.25f*o1l.y;
      v.z = 0.5f*(s0l.z*c0.z+o0l.z) + 0.25f*o1l.z;
      v.w = 0.5f*(s0l.w*c0.w+o0l.w) + 0.25f*o1l.w;
      int i0 = idx0P[hbn + n];
      if(i0 >= 0){
        float4 nv = ((const float4*)(new1c + (size_t)i0*32))[lane&7];
        v.x += 0.25f*s1l.x*nv.x; v.y += 0.25f*s1l.y*nv.y;
        v.z += 0.25f*s1l.z*nv.z; v.w += 0.25f*s1l.w*nv.w;
      }
      v.x*=smn; v.y*=smn; v.z*=smn; v.w*=smn;
      *(float4*)&xps[grp][lane*4] = v;
    }
    const float* Wr = Wrel  + (size_t)(h*32+lane)*128;
    const float* Wo = Wroot + (size_t)(h*32+lane)*128;
    float o = bias[h*32+lane];
    for(int k=0;k<32;k++){
      float4 a  = *(const float4*)&aggs[grp][k*4];
      float4 xx = *(const float4*)&xps[grp][k*4];
      float4 wr = ((const float4*)Wr)[k];
      float4 wo = ((const float4*)Wo)[k];
      o += a.x*wr.x + a.y*wr.y + a.z*wr.z + a.w*wr.w;
      o += xx.x*wo.x + xx.y*wo.y + xx.z*wo.z + xx.w*wo.w;
    }
    o = lrelu(o);
    new2c[(size_t)item*32 + lane] = o;
    atomicAdd(&bnsum[h*32+lane], o);
    atomicAdd(&bnsq[h*32+lane], o*o);
  }
}

// ---------- cls: block per (graph,class) ----------
__global__ __launch_bounds__(256) void k_cls2(const float* __restrict__ cur0,
    const int* __restrict__ idx0P, const float* __restrict__ new1c,
    const int* __restrict__ idx1P, const float* __restrict__ new2c,
    const float* __restrict__ pre2, const int* __restrict__ cnt1,
    const int* __restrict__ wl1, const float* __restrict__ pwc,
    const float* __restrict__ bns0, const float* __restrict__ bnq0,
    const float* __restrict__ g0, const float* __restrict__ b0bn,
    const float* __restrict__ bnsA, const float* __restrict__ bnqA,
    const float* __restrict__ g1v, const float* __restrict__ b1v,
    const float* __restrict__ bnsB, const float* __restrict__ bnqB,
    const float* __restrict__ g2v, const float* __restrict__ b2v,
    const float* __restrict__ gW1, const float* __restrict__ gb1,
    const float* __restrict__ gW2, const float* __restrict__ gb2,
    const float* __restrict__ fW1, const float* __restrict__ fb1,
    const float* __restrict__ fW2, const float* __restrict__ fb2,
    float* __restrict__ yws){
  __shared__ float red[4];
  __shared__ float sc0s[128], of0s[128], s1s[128], o1s[128], s2s[128], o2s[128];
  __shared__ float wc[128];
  __shared__ float patch[256];
  __shared__ int keptL[256];
  __shared__ float keptS[256];
  __shared__ float gateL[256];
  __shared__ __align__(16) float xk[128];
  __shared__ __align__(16) float pooled[128];
  __shared__ int nkept;
  const int t = threadIdx.x;
  const int g = blockIdx.x >> 2, c = blockIdx.x & 3;
  if(t<128){
    float mu = bns0[t]*(1.0f/NN);
    float var = bnq0[t]*(1.0f/NN) - mu*mu;
    float sv = g0[t]*rsqrtf(var+1e-5f);
    sc0s[t]=sv; of0s[t]=b0bn[t]-mu*sv;
    float mu1 = bnsA[t]*(1.0f/NN);
    float var1 = bnqA[t]*(1.0f/NN) - mu1*mu1;
    float s1 = g1v[t]*rsqrtf(var1+1e-5f);
    s1s[t]=s1; o1s[t]=b1v[t]-mu1*s1;
    float mu2 = bnsB[t]*(1.0f/NN);
    float var2 = bnqB[t]*(1.0f/NN) - mu2*mu2;
    float s2 = g2v[t]*rsqrtf(var2+1e-5f);
    s2s[t]=s2; o2s[t]=b2v[t]-mu2*s2;
    wc[t] = pwc[c*128+t];
  }
  patch[t]=0.f;
  __syncthreads();
  int total1 = *cnt1; if(total1 > CAP) total1 = CAP;
  for(int i=t; i<total1; i+=256){
    int wv = wl1[i];
    int n = wv & 0xFFFF, hp = wv>>16;
    if((n>>8)==g){
      float d=0.f;
      for(int l=0;l<32;l++){
        int j = hp*32+l;
        d += new2c[(size_t)i*32+l]*s2s[j]*wc[j];
      }
      atomicAdd(&patch[n&255], 0.25f*d);
    }
  }
  __syncthreads();
  const int n = g*256 + t;
  float sc = pre2[n*4 + c] + patch[t];
  float m = blockMax4(sc, red);
  float e = expf(sc-m);
  float ssum = blockSum4(e, red);
  float sm = e/(ssum+1e-16f);
  float smax = blockMax4(sm, red);
  float thr = fminf(smax - 1e-7f, 0.8f);
  if(t==0) nkept = 0;
  __syncthreads();
  if(sm > thr){
    int p = atomicAdd(&nkept,1);
    keptL[p]=t; keptS[p]=sm;
  }
  __syncthreads();
  const int K = nkept;
  for(int k=0;k<K;k++){
    int ln = keptL[k]; float sv = keptS[k];
    int nn = g*256 + ln;
    if(t<32){
      float4 c0 = ((const float4*)cur0)[nn*32 + t];
      float4 s0l = *(const float4*)&sc0s[t*4];
      float4 o0l = *(const float4*)&of0s[t*4];
      float4 s1l = *(const float4*)&s1s[t*4];
      float4 o1l = *(const float4*)&o1s[t*4];
      float4 s2l = *(const float4*)&s2s[t*4];
      float4 o2l = *(const float4*)&o2s[t*4];
      int hb = t>>3;
      float4 v1;
      v1.x = 0.5f*(s0l.x*c0.x+o0l.x) + 0.25f*o1l.x;
      v1.y = 0.5f*(s0l.y*c0.y+o0l.y) + 0.25f*o1l.y;
      v1.z = 0.5f*(s0l.z*c0.z+o0l.z) + 0.25f*o1l.z;
      v1.w = 0.5f*(s0l.w*c0.w+o0l.w) + 0.25f*o1l.w;
      int i0 = idx0P[(size_t)hb*NN + nn];
      if(i0 >= 0){
        float4 nv = ((const float4*)(new1c + (size_t)i0*32))[t&7];
        v1.x += 0.25f*s1l.x*nv.x; v1.y += 0.25f*s1l.y*nv.y;
        v1.z += 0.25f*s1l.z*nv.z; v1.w += 0.25f*s1l.w*nv.w;
      }
      float4 v2;
      v2.x = 0.5f*v1.x + 0.25f*o2l.x;
      v2.y = 0.5f*v1.y + 0.25f*o2l.y;
      v2.z = 0.5f*v1.z + 0.25f*o2l.z;
      v2.w = 0.5f*v1.w + 0.25f*o2l.w;
      int i1 = idx1P[(size_t)hb*NN + nn];
      if(i1 >= 0){
        float4 nv = ((const float4*)(new2c + (size_t)i1*32))[t&7];
        v2.x += 0.25f*s2l.x*nv.x; v2.y += 0.25f*s2l.y*nv.y;
        v2.z += 0.25f*s2l.z*nv.z; v2.w += 0.25f*s2l.w*nv.w;
      }
      v2.x*=sv; v2.y*=sv; v2.z*=sv; v2.w*=sv;
      *(float4*)&xk[t*4] = v2;
    }
    __syncthreads();
    float part = 0.f;
    if(t<128){
      const float* W = gW1 + (size_t)c*16384 + (size_t)t*128;
      float a = gb1[c*128+t];
      for(int f=0;f<32;f++){
        float4 xv = *(const float4*)&xk[f*4];
        float4 wv = ((const float4*)W)[f];
        a += xv.x*wv.x + xv.y*wv.y + xv.z*wv.z + xv.w*wv.w;
      }
      part = lrelu(a) * gW2[c*128+t];
    }
    float gs = blockSum4(part, red);
    if(t==0) gateL[k] = gs + gb2[c];
    __syncthreads();
  }
  float gv = (t<K)? gateL[t] : -INFINITY;
  float gm = blockMax4(gv, red);
  float ge = (t<K)? expf(gv-gm) : 0.f;
  float gsum = blockSum4(ge, red);
  if(t<K) gateL[t] = ge/(gsum+1e-16f);
  __syncthreads();
  if(t<128){
    int hb = t>>5, l = t&31;
    float acc = 0.f;
    for(int k=0;k<K;k++){
      int nn = g*256 + keptL[k];
      float c0 = cur0[(size_t)nn*128 + t];
      float v1 = 0.5f*(sc0s[t]*c0 + of0s[t]) + 0.25f*o1s[t];
      int i0 = idx0P[(size_t)hb*NN + nn];
      if(i0 >= 0) v1 += 0.25f*s1s[t]*new1c[(size_t)i0*32 + l];
      float v2 = 0.5f*v1 + 0.25f*o2s[t];
      int i1 = idx1P[(size_t)hb*NN + nn];
      if(i1 >= 0) v2 += 0.25f*s2s[t]*new2c[(size_t)i1*32 + l];
      acc += gateL[k]*keptS[k]*v2;
    }
    pooled[t]=acc;
  }
  __syncthreads();
  float part2=0.f;
  if(t<128){
    const float* F = fW1 + (size_t)c*16384 + (size_t)t*128;
    float a = fb1[c*128+t];
    for(int f=0;f<32;f++){
      float4 xv = *(const float4*)&pooled[f*4];
      float4 wv = ((const float4*)F)[f];
      a += xv.x*wv.x + xv.y*wv.y + xv.z*wv.z + xv.w*wv.w;
    }
    part2 = lrelu(a) * fW2[c*128+t];
  }
  float ysum = blockSum4(part2, red);
  if(t==0) yws[g*4+c] = ysum + fb2[c];
}

// ---------- final per-graph log_softmax over 4 class logits ----------
__global__ __launch_bounds__(256) void k_clsfin(const float* __restrict__ yws,
                                                float* __restrict__ out){
  const int g = threadIdx.x;
  float4 y = ((const float4*)yws)[g];
  float m = fmaxf(fmaxf(y.x,y.y), fmaxf(y.z,y.w));
  float l = logf(expf(y.x-m)+expf(y.y-m)+expf(y.z-m)+expf(y.w-m));
  ((float4*)out)[g] = make_float4(y.x-m-l, y.y-m-l, y.z-m-l, y.w-m-l);
}

extern "C" void kernel_launch(void* const* d_in, const int* in_sizes, int n_in,
                              void* d_out, int out_size, void* d_ws, size_t ws_size,
                              hipStream_t stream){
  (void)in_sizes; (void)n_in; (void)out_size; (void)ws_size;
  const float* x     = (const float*)d_in[0];
  const int*   ei    = (const int*)d_in[1];
  const float* Wrel0 = (const float*)d_in[3];
  const float* Wroot0= (const float*)d_in[4];
  const float* b0    = (const float*)d_in[5];
  const float* bn0g  = (const float*)d_in[6];
  const float* bn0b  = (const float*)d_in[7];
  const float* bpw   = (const float*)d_in[8];
  const float* bWrel = (const float*)d_in[9];
  const float* bWroot= (const float*)d_in[10];
  const float* bbv   = (const float*)d_in[11];
  const float* bbng  = (const float*)d_in[12];
  const float* bbnb  = (const float*)d_in[13];
  const float* cpw   = (const float*)d_in[14];
  const float* gW1   = (const float*)d_in[15];
  const float* gb1   = (const float*)d_in[16];
  const float* gW2   = (const float*)d_in[17];
  const float* gb2   = (const float*)d_in[18];
  const float* fW1   = (const float*)d_in[19];
  const float* fb1   = (const float*)d_in[20];
  const float* fW2   = (const float*)d_in[21];
  const float* fb2   = (const float*)d_in[22];

  char* ws = (char*)d_ws;
  float* cur0  = (float*)(ws + 0);                  // 33.55 MB
  float* new1c = (float*)(ws + 33554432ull);        // 16.78 MB (CAP*32 floats)
  float* new2c = (float*)(ws + 50331648ull);        // 16.78 MB (aliases agg0)
  float* agg0  = new2c;                             // dead before new2c written
  int*   csr   = (int*)(ws + 67108864ull);          // 2 MB
  float* scores0=(float*)(ws + 69206016ull);        // 1 MB (sm4_0 aliases)
  float* sm40  = scores0;
  float* pre1  = (float*)(ws + 70254592ull);        // 1 MB (sm4_1 aliases)
  float* sm41  = pre1;
  float* pre2  = (float*)(ws + 71303168ull);        // 1 MB
  int*   wl0   = (int*)(ws + 72351744ull);          // 512 KB
  int*   wl1   = (int*)(ws + 72876032ull);          // 512 KB
  int*   offs  = (int*)(ws + 73400320ull);          // 256 KB + 4
  int*   cursor= (int*)(ws + 73666560ull);          // 256 KB
  int*   idx0P = (int*)(ws + 73928704ull);          // 1 MB (4 planes, always written)
  int*   idx1P = (int*)(ws + 74977280ull);          // 1 MB
  char*  Z     = ws + 76025856ull;                  // zero-init region
  int*   deg   = (int*)Z;                           // 256 KB
  float* bnsum0= (float*)(Z + 262144);
  float* bnsq0 = (float*)(Z + 262656);
  float* bnA   = (float*)(Z + 263168);
  float* bqA   = (float*)(Z + 263680);
  float* bnB   = (float*)(Z + 264192);
  float* bqB   = (float*)(Z + 264704);
  int*   cnt0  = (int*)(Z + 265216);
  int*   cnt1  = (int*)(Z + 265220);
  float* yws   = (float*)(Z + 266240);              // 4 KB

  hipMemsetAsync(Z, 0, 270336, stream);

  // CSR by dst
  k_count  <<<2048,256,0,stream>>>(ei, deg);
  k_scan   <<<1,1024,0,stream>>>(deg, offs, cursor);
  k_scatter<<<2048,256,0,stream>>>(ei, cursor, csr);

  // conv0 -> lrelu (+ fused bn0 stats; bn0 apply stays folded downstream)
  k_agg0    <<<4096,256,0,stream>>>(x, offs, csr, agg0);
  k_conv0mm <<<512,256,0,stream>>>(agg0, x, Wrel0, Wroot0, b0, cur0, bnsum0, bnsq0);

  // single pass: scores for pool0 + pre-scores for pool1/cls
  k_scores<<<8192,256,0,stream>>>(cur0, bnsum0, bnsq0, bn0g,
                                  bpw, bpw + 512, cpw, scores0, pre1, pre2);

  // pool layer 0 select (wave-per-head, barrier-free)
  k_poolselW<<<256,256,0,stream>>>(scores0, 0.7f, sm40, cnt0, wl0, idx0P);

  // layer-0 conv on kept items
  k_blockconv0<<<256,256,0,stream>>>(cur0, offs, csr, idx0P, sm40, cnt0, wl0,
                                     bWrel, bWroot, bbv, new1c, bnA, bqA,
                                     bnsum0, bnsq0, bn0g, bn0b);

  // pool layer 1 select (patches pre1 with layer-1 corr, pre2 partially)
  k_poolsel1<<<256,256,0,stream>>>(pre1, pre2, cnt0, wl0, new1c,
                                   bnA, bqA, bbng,
                                   bpw + 512, cpw,
                                   0.7f, sm41, cnt1, wl1, idx1P);

  // layer-1 conv on kept items (rows reconstructed)
  k_blockconv1<<<256,256,0,stream>>>(cur0, offs, csr, idx0P, new1c,
                                     idx1P, sm41, cnt1, wl1,
                                     bWrel + 16384, bWroot + 16384, bbv + 128,
                                     new2c, bnB, bqB,
                                     bnsum0, bnsq0, bn0g, bn0b,
                                     bnA, bqA, bbng, bbnb);

  // classification heads (patch pre2 with layer-2 corr in-block)
  k_cls2<<<1024,256,0,stream>>>(cur0, idx0P, new1c, idx1P, new2c,
                                pre2, cnt1, wl1, cpw,
                                bnsum0, bnsq0, bn0g, bn0b,
                                bnA, bqA, bbng, bbnb,
                                bnB, bqB, bbng + 128, bbnb + 128,
                                gW1, gb1, gW2, gb2, fW1, fb1, fW2, fb2, yws);
  k_clsfin<<<1,256,0,stream>>>(yws, (float*)d_out);
}